// Round 8
// baseline (119.590 us; speedup 1.0000x reference)
//
#include <hip/hip_runtime.h>

// NewtonImplicitNet via Picard iteration, MFMA, 2-blocks-per-CU edition.
// R7 post-mortem: 48us, VALUBusy 25%, 1 wave/SIMD -> per-iter serial chain
// (write -> barrier -> read -> 4-dep MFMA -> tanh) unhidden; A-frag reads
// fetched 16 rows of which only 8 nonzero; 1.5M LDS bank conflicts.
// R8: RPB 8->4 (grid 512 = 2 blocks/CU: two independent chains per SIMD),
// exec-masked A-frag reads (lo16 < RPB -> 4x less LDS read traffic),
// NIT 14->12. Math otherwise identical (f16 iteration, f16 hi/lo input
// GEMM, f32 accumulator carried across implicit blocks).

#define B_ROWS  2048
#define D_IN    784
#define UNITS   128
#define D_OUT   10
#define RPB     4       // rows per block -> 512 blocks = 2 blocks/CU
#define NIT     12      // even (double-buffer parity)
#define ZSTR    136     // f16 Z row stride (68 dwords: +4-bank rotate/row)

typedef _Float16 f16x8 __attribute__((ext_vector_type(8)));
typedef float    f32x4 __attribute__((ext_vector_type(4)));

__device__ __forceinline__ float rcp_fast(float x) { return __builtin_amdgcn_rcpf(x); }

__device__ __forceinline__ float tanh_fast(float x) {
  float e = __expf(2.0f * x);
  return 1.0f - 2.0f * rcp_fast(e + 1.0f);
}

__device__ __forceinline__ f16x8 cvt8(f32x4 a, f32x4 b) {
  f16x8 r;
  r[0] = (_Float16)a[0]; r[1] = (_Float16)a[1]; r[2] = (_Float16)a[2]; r[3] = (_Float16)a[3];
  r[4] = (_Float16)b[0]; r[5] = (_Float16)b[1]; r[6] = (_Float16)b[2]; r[7] = (_Float16)b[3];
  return r;
}
__device__ __forceinline__ f16x8 res8(f32x4 a, f32x4 b, f16x8 hi) {
  f16x8 r;
  r[0] = (_Float16)(a[0] - (float)hi[0]); r[1] = (_Float16)(a[1] - (float)hi[1]);
  r[2] = (_Float16)(a[2] - (float)hi[2]); r[3] = (_Float16)(a[3] - (float)hi[3]);
  r[4] = (_Float16)(b[0] - (float)hi[4]); r[5] = (_Float16)(b[1] - (float)hi[5]);
  r[6] = (_Float16)(b[2] - (float)hi[6]); r[7] = (_Float16)(b[3] - (float)hi[7]);
  return r;
}

#define MFMA(a, b, c) __builtin_amdgcn_mfma_f32_16x16x32_f16((a), (b), (c), 0, 0, 0)

// Fragment conventions (validated R4-R7):
//   A: lane holds A[m=lo16][k = 32s + quad*8 + j], j=0..7
//   B: lane holds B[k = 32s + quad*8 + j][n=lo16]  (= Wrow[n][k..] row-major)
//   C/D: lane holds D[m = quad*4 + i][n=lo16], i=0..3

__global__ __launch_bounds__(256, 2) void fused_net(
    const float* __restrict__ x,
    const float* __restrict__ W_in,
    const float* __restrict__ b_in,
    const float* __restrict__ W1,
    const float* __restrict__ W2,
    const float* __restrict__ W3,
    const float* __restrict__ W4,
    const float* __restrict__ W_out,
    const float* __restrict__ b_out,
    float* __restrict__ out)
{
  __shared__ __align__(16) _Float16 Zb[2][16][ZSTR];   // rows RPB..15 stay zero
  __shared__ __align__(16) float    Xs[RPB][D_IN];     // staged x rows (12.5 KB)
  __shared__ __align__(16) float    Wo[D_OUT * UNITS]; // staged W_out (5 KB)
  __shared__ float Bo[D_OUT];
  __shared__ __align__(16) float    Zh[RPB][UNITS];    // final z4 for head
  __shared__ float Lg[RPB][D_OUT];

  const int t    = threadIdx.x;
  const int wave = t >> 6;        // 0..3, N-chunk: units [32w, 32w+32)
  const int l    = t & 63;
  const int lo16 = l & 15;
  const int quad = l >> 4;
  const int u0   = wave * 32;
  const int r0   = blockIdx.x * RPB;

  // early independent scalar loads (latency hidden under staging)
  const float bi0 = b_in[u0 + lo16];
  const float bi1 = b_in[u0 + 16 + lo16];

  const float* const Ws[4] = {W1, W2, W3, W4};

  // ---- prefetch W-frag raw data for wb=0 (consumed after staging) ----
  f32x4 raw[16];
  {
    const float* a = Ws[0] + (size_t)(u0 + lo16) * UNITS;
    const float* b = Ws[0] + (size_t)(u0 + 16 + lo16) * UNITS;
#pragma unroll
    for (int s = 0; s < 4; ++s) {
      const int k = s * 32 + quad * 8;
      raw[s * 2]         = *(const f32x4*)(a + k);
      raw[s * 2 + 1]     = *(const f32x4*)(a + k + 4);
      raw[8 + s * 2]     = *(const f32x4*)(b + k);
      raw[8 + s * 2 + 1] = *(const f32x4*)(b + k + 4);
    }
  }

  // ---- coalesced staging bursts (independent loads -> pipelined) ----
#pragma unroll 1
  for (int idx = t; idx < RPB * (D_IN / 4); idx += 256) {
    const int row = idx / (D_IN / 4);
    const int c4  = idx % (D_IN / 4);
    *((f32x4*)&Xs[row][0] + c4) = *((const f32x4*)(x + (size_t)(r0 + row) * D_IN) + c4);
  }
#pragma unroll 1
  for (int idx = t; idx < D_OUT * UNITS / 4; idx += 256)
    *((f32x4*)Wo + idx) = *((const f32x4*)W_out + idx);
  if (t < D_OUT) Bo[t] = b_out[t];
  // zero Zb rows RPB..15 in both buffers (never written again)
#pragma unroll 1
  for (int idx = t; idx < 2 * (16 - RPB) * (ZSTR / 2); idx += 256) {
    const int buf = idx / ((16 - RPB) * (ZSTR / 2));
    const int rem = idx % ((16 - RPB) * (ZSTR / 2));
    ((unsigned*)&Zb[buf][RPB + rem / (ZSTR / 2)][0])[rem % (ZSTR / 2)] = 0u;
  }
  __syncthreads();

  // ---- input GEMM: xf = x @ W_in.T + b_in (f16 hi/lo 3-term), x from LDS ----
  f32x4 acc0 = {0.f, 0.f, 0.f, 0.f};
  f32x4 acc1 = {0.f, 0.f, 0.f, 0.f};
  const float* wr0 = W_in + (size_t)(u0 + lo16) * D_IN;
  const float* wr1 = W_in + (size_t)(u0 + 16 + lo16) * D_IN;
  f32x4 p0a, p0b, p1a, p1b;         // depth-1 prefetch of W_in
  {
    const int kc = quad * 8;        // s=0 always valid
    p0a = *(const f32x4*)(wr0 + kc);  p0b = *(const f32x4*)(wr0 + kc + 4);
    p1a = *(const f32x4*)(wr1 + kc);  p1b = *(const f32x4*)(wr1 + kc + 4);
  }
#pragma unroll 1
  for (int s = 0; s < 25; ++s) {
    f32x4 c0a = p0a, c0b = p0b, c1a = p1a, c1b = p1b;
    if (s < 24) {
      const int kn  = (s + 1) * 32 + quad * 8;
      const int knc = (kn > 776) ? 776 : kn;
      p0a = *(const f32x4*)(wr0 + knc);  p0b = *(const f32x4*)(wr0 + knc + 4);
      p1a = *(const f32x4*)(wr1 + knc);  p1b = *(const f32x4*)(wr1 + knc + 4);
    }
    const int k  = s * 32 + quad * 8;
    const int kc = (k > 776) ? 776 : k;
    const bool act = ((k + 8) <= D_IN) && (lo16 < RPB);   // A rows RPB..15 zero
    f32x4 xa = *(const f32x4*)&Xs[lo16 & (RPB - 1)][kc];
    f32x4 xb = *(const f32x4*)&Xs[lo16 & (RPB - 1)][kc + 4];
    f16x8 ahi = cvt8(xa, xb);
    f16x8 alo = res8(xa, xb, ahi);
    if (!act) { ahi = (f16x8){}; alo = (f16x8){}; }
    f16x8 bh = cvt8(c0a, c0b);
    f16x8 bl = res8(c0a, c0b, bh);
    acc0 = MFMA(ahi, bh, acc0);
    acc0 = MFMA(ahi, bl, acc0);
    acc0 = MFMA(alo, bh, acc0);
    bh = cvt8(c1a, c1b);
    bl = res8(c1a, c1b, bh);
    acc1 = MFMA(ahi, bh, acc1);
    acc1 = MFMA(ahi, bl, acc1);
    acc1 = MFMA(alo, bh, acc1);
  }
  f32x4 xf0, xf1;   // fixed-point input, f32, D-layout
#pragma unroll
  for (int i = 0; i < 4; ++i) { xf0[i] = acc0[i] + bi0; xf1[i] = acc1[i] + bi1; }

  // masked A-frag read: only lanes with real rows touch LDS (exec-masked)
#define ZREAD(pbuf, off) \
  ((lo16 < RPB) ? *(const f16x8*)&Zb[pbuf][lo16][(off) + quad * 8] : (f16x8){})

  // ---- 4 implicit blocks: z = tanh(z @ W.T + xf), Picard ----
#pragma unroll 1
  for (int wb = 0; wb < 4; ++wb) {
    f16x8 wf[2][4];
#pragma unroll
    for (int s = 0; s < 4; ++s) {
      wf[0][s] = cvt8(raw[s * 2], raw[s * 2 + 1]);
      wf[1][s] = cvt8(raw[8 + s * 2], raw[8 + s * 2 + 1]);
    }
    if (wb < 3) {   // prefetch next W during this block's Picard loop
      const float* a = Ws[wb + 1] + (size_t)(u0 + lo16) * UNITS;
      const float* b = Ws[wb + 1] + (size_t)(u0 + 16 + lo16) * UNITS;
#pragma unroll
      for (int s = 0; s < 4; ++s) {
        const int k = s * 32 + quad * 8;
        raw[s * 2]         = *(const f32x4*)(a + k);
        raw[s * 2 + 1]     = *(const f32x4*)(a + k + 4);
        raw[8 + s * 2]     = *(const f32x4*)(b + k);
        raw[8 + s * 2 + 1] = *(const f32x4*)(b + k + 4);
      }
    }

    // z0 = tanh(xf) into buf 0 (rows 0..RPB-1 = quad 0 only)
    if (quad == 0) {
#pragma unroll
      for (int i = 0; i < 4; ++i) {
        Zb[0][i][u0 + lo16]      = (_Float16)tanh_fast(xf0[i]);
        Zb[0][i][u0 + 16 + lo16] = (_Float16)tanh_fast(xf1[i]);
      }
    }
    __syncthreads();

    int p = 0;
#pragma unroll 1
    for (int it = 0; it < NIT - 1; ++it) {
      f16x8 a0 = ZREAD(p, 0);
      f16x8 a1 = ZREAD(p, 32);
      f16x8 a2 = ZREAD(p, 64);
      f16x8 a3 = ZREAD(p, 96);
      f32x4 c0 = xf0;   // C = xf: "+x" free via the accumulator
      f32x4 c1 = xf1;
      c0 = MFMA(a0, wf[0][0], c0);  c1 = MFMA(a0, wf[1][0], c1);
      c0 = MFMA(a1, wf[0][1], c0);  c1 = MFMA(a1, wf[1][1], c1);
      c0 = MFMA(a2, wf[0][2], c0);  c1 = MFMA(a2, wf[1][2], c1);
      c0 = MFMA(a3, wf[0][3], c0);  c1 = MFMA(a3, wf[1][3], c1);
      const int q = p ^ 1;
      if (quad == 0) {
#pragma unroll
        for (int i = 0; i < 4; ++i) {
          Zb[q][i][u0 + lo16]      = (_Float16)tanh_fast(c0[i]);
          Zb[q][i][u0 + 16 + lo16] = (_Float16)tanh_fast(c1[i]);
        }
      }
      __syncthreads();
      p = q;
    }
    // final iteration: output stays f32 in regs -> next block's xf
    {
      f16x8 a0 = ZREAD(p, 0);
      f16x8 a1 = ZREAD(p, 32);
      f16x8 a2 = ZREAD(p, 64);
      f16x8 a3 = ZREAD(p, 96);
      f32x4 c0 = xf0;
      f32x4 c1 = xf1;
      c0 = MFMA(a0, wf[0][0], c0);  c1 = MFMA(a0, wf[1][0], c1);
      c0 = MFMA(a1, wf[0][1], c0);  c1 = MFMA(a1, wf[1][1], c1);
      c0 = MFMA(a2, wf[0][2], c0);  c1 = MFMA(a2, wf[1][2], c1);
      c0 = MFMA(a3, wf[0][3], c0);  c1 = MFMA(a3, wf[1][3], c1);
#pragma unroll
      for (int i = 0; i < 4; ++i) { xf0[i] = tanh_fast(c0[i]); xf1[i] = tanh_fast(c1[i]); }
      // NIT even: final read was buf 1; buf 0's last readers passed their
      // barrier at it = NIT-3; next wb's z0 write to buf 0 is race-free.
    }
  }

  // ---- head: logits = z4 @ W_out.T + b_out, softmax ----
  if (quad == 0) {
#pragma unroll
    for (int i = 0; i < 4; ++i) {
      Zh[i][u0 + lo16]      = xf0[i];
      Zh[i][u0 + 16 + lo16] = xf1[i];
    }
  }
  __syncthreads();

  if (t < RPB * D_OUT) {
    const int r = t / D_OUT, c = t % D_OUT;
    float s = Bo[c];
    const float* wo = &Wo[c * UNITS];
#pragma unroll
    for (int k = 0; k < UNITS; k += 4) {
      f32x4 zv = *(const f32x4*)&Zh[r][k];
      f32x4 wv = *(const f32x4*)&wo[k];
      s = fmaf(zv[0], wv[0], s);
      s = fmaf(zv[1], wv[1], s);
      s = fmaf(zv[2], wv[2], s);
      s = fmaf(zv[3], wv[3], s);
    }
    Lg[r][c] = s;
  }
  __syncthreads();
  if (t < RPB) {
    float m = Lg[t][0];
#pragma unroll
    for (int c = 1; c < D_OUT; ++c) m = fmaxf(m, Lg[t][c]);
    float e[D_OUT];
    float sum = 0.f;
#pragma unroll
    for (int c = 0; c < D_OUT; ++c) { e[c] = __expf(Lg[t][c] - m); sum += e[c]; }
    const float rs = rcp_fast(sum);
    float* orow = out + (size_t)(r0 + t) * D_OUT;
#pragma unroll
    for (int c = 0; c < D_OUT; ++c) orow[c] = e[c] * rs;
  }
}

extern "C" void kernel_launch(void* const* d_in, const int* in_sizes, int n_in,
                              void* d_out, int out_size, void* d_ws, size_t ws_size,
                              hipStream_t stream) {
  const float* x     = (const float*)d_in[0];
  const float* W_in  = (const float*)d_in[1];
  const float* b_in  = (const float*)d_in[2];
  const float* W1    = (const float*)d_in[3];
  const float* W2    = (const float*)d_in[4];
  const float* W3    = (const float*)d_in[5];
  const float* W4    = (const float*)d_in[6];
  const float* W_out = (const float*)d_in[7];
  const float* b_out = (const float*)d_in[8];
  float* outp = (float*)d_out;

  dim3 grid(B_ROWS / RPB);      // 512 blocks x 4 waves = 2 blocks/CU
  dim3 block(256);
  hipLaunchKernelGGL(fused_net, grid, block, 0, stream,
                     x, W_in, b_in, W1, W2, W3, W4, W_out, b_out, outp);
}

// Round 9
// 105.856 us; speedup vs baseline: 1.1297x; 1.1297x over previous
//
#include <hip/hip_runtime.h>

// NewtonImplicitNet via Picard iteration, MFMA, 8-wave N-split edition.
// R8 post-mortem: RPB=4 quarter-filled the M=16 tile -> per-CU issue work
// (MFMA + trans-pipe tanh) DOUBLED vs R7; throughput-bound at 44% VALUBusy.
// R9: 256 blocks x 8 waves (512 thr), RPB=8, N-split 8 (wave owns ONE
// 16-unit tile). Per-CU work == R7 (64 trans + 32 MFMA per iter), but
// 2 waves/SIMD overlap the serial chain (MFMA chain / tanh / LDS turnaround).
// Strictly dominates R7 (same work, 2x overlap) and R8 (half work, same
// overlap). Math identical: NIT=12, f16 iteration, f16 hi/lo input GEMM,
// f32 accumulator carried across implicit blocks.

#define B_ROWS  2048
#define D_IN    784
#define UNITS   128
#define D_OUT   10
#define RPB     8       // rows per block -> 256 blocks, rows 0..7 real in M=16
#define THREADS 512
#define NIT     12      // even (double-buffer parity)
#define ZSTR    136     // f16 Z row stride (68 dwords: +4-bank rotate/row)

typedef _Float16 f16x8 __attribute__((ext_vector_type(8)));
typedef float    f32x4 __attribute__((ext_vector_type(4)));

__device__ __forceinline__ float rcp_fast(float x) { return __builtin_amdgcn_rcpf(x); }

__device__ __forceinline__ float tanh_fast(float x) {
  float e = __expf(2.0f * x);
  return 1.0f - 2.0f * rcp_fast(e + 1.0f);
}

__device__ __forceinline__ f16x8 cvt8(f32x4 a, f32x4 b) {
  f16x8 r;
  r[0] = (_Float16)a[0]; r[1] = (_Float16)a[1]; r[2] = (_Float16)a[2]; r[3] = (_Float16)a[3];
  r[4] = (_Float16)b[0]; r[5] = (_Float16)b[1]; r[6] = (_Float16)b[2]; r[7] = (_Float16)b[3];
  return r;
}
__device__ __forceinline__ f16x8 res8(f32x4 a, f32x4 b, f16x8 hi) {
  f16x8 r;
  r[0] = (_Float16)(a[0] - (float)hi[0]); r[1] = (_Float16)(a[1] - (float)hi[1]);
  r[2] = (_Float16)(a[2] - (float)hi[2]); r[3] = (_Float16)(a[3] - (float)hi[3]);
  r[4] = (_Float16)(b[0] - (float)hi[4]); r[5] = (_Float16)(b[1] - (float)hi[5]);
  r[6] = (_Float16)(b[2] - (float)hi[6]); r[7] = (_Float16)(b[3] - (float)hi[7]);
  return r;
}

#define MFMA(a, b, c) __builtin_amdgcn_mfma_f32_16x16x32_f16((a), (b), (c), 0, 0, 0)

// Fragment conventions (validated R4-R8):
//   A: lane holds A[m=lo16][k = 32s + quad*8 + j], j=0..7
//   B: lane holds B[k = 32s + quad*8 + j][n=lo16]  (= Wrow[n][k..] row-major)
//   C/D: lane holds D[m = quad*4 + i][n=lo16], i=0..3

__global__ __launch_bounds__(THREADS, 2) void fused_net(
    const float* __restrict__ x,
    const float* __restrict__ W_in,
    const float* __restrict__ b_in,
    const float* __restrict__ W1,
    const float* __restrict__ W2,
    const float* __restrict__ W3,
    const float* __restrict__ W4,
    const float* __restrict__ W_out,
    const float* __restrict__ b_out,
    float* __restrict__ out)
{
  __shared__ __align__(16) _Float16 Zb[2][16][ZSTR];   // rows RPB..15 stay zero
  __shared__ __align__(16) float    Xs[RPB][D_IN];     // staged x rows (25 KB)
  __shared__ __align__(16) float    Wo[D_OUT * UNITS]; // staged W_out (5 KB)
  __shared__ float Bo[D_OUT];
  __shared__ __align__(16) float    Zh[RPB][UNITS];    // final z4 for head
  __shared__ float Lg[RPB][D_OUT];

  const int t    = threadIdx.x;
  const int wave = t >> 6;        // 0..7, N-tile: units [16w, 16w+16)
  const int l    = t & 63;
  const int lo16 = l & 15;
  const int quad = l >> 4;
  const int u0   = wave * 16;
  const int r0   = blockIdx.x * RPB;

  // early independent scalar load (latency hidden under staging)
  const float bi = b_in[u0 + lo16];

  const float* const Ws[4] = {W1, W2, W3, W4};

  // ---- prefetch W-frag raw data for wb=0 (consumed after input GEMM) ----
  f32x4 raw[8];
  {
    const float* a = Ws[0] + (size_t)(u0 + lo16) * UNITS;
#pragma unroll
    for (int s = 0; s < 4; ++s) {
      const int k = s * 32 + quad * 8;
      raw[s * 2]     = *(const f32x4*)(a + k);
      raw[s * 2 + 1] = *(const f32x4*)(a + k + 4);
    }
  }

  // ---- coalesced staging bursts (independent loads -> pipelined) ----
#pragma unroll 1
  for (int idx = t; idx < RPB * (D_IN / 4); idx += THREADS) {
    const int row = idx / (D_IN / 4);
    const int c4  = idx % (D_IN / 4);
    *((f32x4*)&Xs[row][0] + c4) = *((const f32x4*)(x + (size_t)(r0 + row) * D_IN) + c4);
  }
  if (t < D_OUT * UNITS / 4)
    *((f32x4*)Wo + t) = *((const f32x4*)W_out + t);
  if (t < D_OUT) Bo[t] = b_out[t];
  // zero Zb rows RPB..15 in both buffers (never written again)
#pragma unroll 1
  for (int idx = t; idx < 2 * (16 - RPB) * (ZSTR / 2); idx += THREADS) {
    const int buf = idx / ((16 - RPB) * (ZSTR / 2));
    const int rem = idx % ((16 - RPB) * (ZSTR / 2));
    ((unsigned*)&Zb[buf][RPB + rem / (ZSTR / 2)][0])[rem % (ZSTR / 2)] = 0u;
  }
  __syncthreads();

  // ---- input GEMM: xf = x @ W_in.T + b_in (f16 hi/lo 3-term), x from LDS ----
  f32x4 acc = {0.f, 0.f, 0.f, 0.f};
  const float* wr = W_in + (size_t)(u0 + lo16) * D_IN;
  f32x4 pa, pb;                     // depth-1 prefetch of W_in (1 row/lane)
  {
    const int kc = quad * 8;        // s=0 always valid
    pa = *(const f32x4*)(wr + kc);
    pb = *(const f32x4*)(wr + kc + 4);
  }
#pragma unroll 1
  for (int s = 0; s < 25; ++s) {
    f32x4 ca = pa, cb = pb;
    if (s < 24) {
      const int kn  = (s + 1) * 32 + quad * 8;
      const int knc = (kn > 776) ? 776 : kn;
      pa = *(const f32x4*)(wr + knc);
      pb = *(const f32x4*)(wr + knc + 4);
    }
    const int k  = s * 32 + quad * 8;
    const int kc = (k > 776) ? 776 : k;
    const bool act = ((k + 8) <= D_IN) && (lo16 < RPB);   // A rows RPB..15 zero
    f32x4 xa = *(const f32x4*)&Xs[lo16 & (RPB - 1)][kc];
    f32x4 xb = *(const f32x4*)&Xs[lo16 & (RPB - 1)][kc + 4];
    f16x8 ahi = cvt8(xa, xb);
    f16x8 alo = res8(xa, xb, ahi);
    if (!act) { ahi = (f16x8){}; alo = (f16x8){}; }
    f16x8 bh = cvt8(ca, cb);
    f16x8 bl = res8(ca, cb, bh);
    acc = MFMA(ahi, bh, acc);
    acc = MFMA(ahi, bl, acc);
    acc = MFMA(alo, bh, acc);
  }
  f32x4 xf;   // fixed-point input, f32, D-layout
#pragma unroll
  for (int i = 0; i < 4; ++i) xf[i] = acc[i] + bi;

  // masked A-frag read: only lanes with real rows touch LDS (exec-masked)
#define ZREAD(pbuf, off) \
  ((lo16 < RPB) ? *(const f16x8*)&Zb[pbuf][lo16][(off) + quad * 8] : (f16x8){})

  // ---- 4 implicit blocks: z = tanh(z @ W.T + xf), Picard ----
#pragma unroll 1
  for (int wb = 0; wb < 4; ++wb) {
    f16x8 wf[4];
#pragma unroll
    for (int s = 0; s < 4; ++s)
      wf[s] = cvt8(raw[s * 2], raw[s * 2 + 1]);
    if (wb < 3) {   // prefetch next W during this block's Picard loop
      const float* a = Ws[wb + 1] + (size_t)(u0 + lo16) * UNITS;
#pragma unroll
      for (int s = 0; s < 4; ++s) {
        const int k = s * 32 + quad * 8;
        raw[s * 2]     = *(const f32x4*)(a + k);
        raw[s * 2 + 1] = *(const f32x4*)(a + k + 4);
      }
    }

    // z0 = tanh(xf) into buf 0 (rows 0..7 = quads 0,1)
    if (quad < 2) {
#pragma unroll
      for (int i = 0; i < 4; ++i)
        Zb[0][quad * 4 + i][u0 + lo16] = (_Float16)tanh_fast(xf[i]);
    }
    __syncthreads();

    int p = 0;
#pragma unroll 1
    for (int it = 0; it < NIT - 1; ++it) {
      f16x8 a0 = ZREAD(p, 0);
      f16x8 a1 = ZREAD(p, 32);
      f16x8 a2 = ZREAD(p, 64);
      f16x8 a3 = ZREAD(p, 96);
      f32x4 c = xf;   // C = xf: "+x" free via the accumulator
      c = MFMA(a0, wf[0], c);
      c = MFMA(a1, wf[1], c);
      c = MFMA(a2, wf[2], c);
      c = MFMA(a3, wf[3], c);
      const int q = p ^ 1;
      if (quad < 2) {
#pragma unroll
        for (int i = 0; i < 4; ++i)
          Zb[q][quad * 4 + i][u0 + lo16] = (_Float16)tanh_fast(c[i]);
      }
      __syncthreads();
      p = q;
    }
    // final iteration: output stays f32 in regs -> next block's xf
    {
      f16x8 a0 = ZREAD(p, 0);
      f16x8 a1 = ZREAD(p, 32);
      f16x8 a2 = ZREAD(p, 64);
      f16x8 a3 = ZREAD(p, 96);
      f32x4 c = xf;
      c = MFMA(a0, wf[0], c);
      c = MFMA(a1, wf[1], c);
      c = MFMA(a2, wf[2], c);
      c = MFMA(a3, wf[3], c);
#pragma unroll
      for (int i = 0; i < 4; ++i) xf[i] = tanh_fast(c[i]);
      // NIT even: final read was buf 1; buf 0's last readers passed their
      // in-loop barrier; next wb's z0 write (buf 0) is race-free.
    }
  }

  // ---- head: logits = z4 @ W_out.T + b_out, softmax ----
  if (quad < 2) {
#pragma unroll
    for (int i = 0; i < 4; ++i)
      Zh[quad * 4 + i][u0 + lo16] = xf[i];
  }
  __syncthreads();

  if (t < RPB * D_OUT) {
    const int r = t / D_OUT, c = t % D_OUT;
    float s = Bo[c];
    const float* wo = &Wo[c * UNITS];
#pragma unroll
    for (int k = 0; k < UNITS; k += 4) {
      f32x4 zv = *(const f32x4*)&Zh[r][k];
      f32x4 wv = *(const f32x4*)&wo[k];
      s = fmaf(zv[0], wv[0], s);
      s = fmaf(zv[1], wv[1], s);
      s = fmaf(zv[2], wv[2], s);
      s = fmaf(zv[3], wv[3], s);
    }
    Lg[r][c] = s;
  }
  __syncthreads();
  if (t < RPB) {
    float m = Lg[t][0];
#pragma unroll
    for (int c = 1; c < D_OUT; ++c) m = fmaxf(m, Lg[t][c]);
    float e[D_OUT];
    float sum = 0.f;
#pragma unroll
    for (int c = 0; c < D_OUT; ++c) { e[c] = __expf(Lg[t][c] - m); sum += e[c]; }
    const float rs = rcp_fast(sum);
    float* orow = out + (size_t)(r0 + t) * D_OUT;
#pragma unroll
    for (int c = 0; c < D_OUT; ++c) orow[c] = e[c] * rs;
  }
}

extern "C" void kernel_launch(void* const* d_in, const int* in_sizes, int n_in,
                              void* d_out, int out_size, void* d_ws, size_t ws_size,
                              hipStream_t stream) {
  const float* x     = (const float*)d_in[0];
  const float* W_in  = (const float*)d_in[1];
  const float* b_in  = (const float*)d_in[2];
  const float* W1    = (const float*)d_in[3];
  const float* W2    = (const float*)d_in[4];
  const float* W3    = (const float*)d_in[5];
  const float* W4    = (const float*)d_in[6];
  const float* W_out = (const float*)d_in[7];
  const float* b_out = (const float*)d_in[8];
  float* outp = (float*)d_out;

  dim3 grid(B_ROWS / RPB);      // 256 blocks x 8 waves = 2 waves/SIMD, full chip
  dim3 block(THREADS);
  hipLaunchKernelGGL(fused_net, grid, block, 0, stream,
                     x, W_in, b_in, W1, W2, W3, W4, W_out, b_out, outp);
}

// Round 10
// 105.767 us; speedup vs baseline: 1.1307x; 1.0008x over previous
//
#include <hip/hip_runtime.h>

// NewtonImplicitNet via Picard iteration, MFMA, conflict-free edition.
// R9 post-mortem: best structure yet (256 blk x 8 waves, N-split 8), but
// (1) A-frag reads 4-way bank-conflicted (ZSTR 136: row stride 68 dw = 4 mod
// 32 aliases with quad stride 4); (2) Xs reads ~8-way conflicted (784 = 16
// mod 32); (3) separate z0 round per wb is mergeable; (4) NIT=12 residual is
// below the f16 noise floor (absmax flat 9.77e-4 from NIT 20 -> 12).
// R10: ZSTR 138 (69 dw = 5 mod 32 -> max 2-way = free), Xs stride 788
// (20 mod 32 = 4*5 -> 8 rows distinct banks), z0 merged into previous wb's
// final iteration (z0' = tanh(tanh(c_final)); 48 -> 40 barrier rounds),
// NIT 10, depth-2 W_in prefetch, Zb shrunk to 8 real rows.

#define B_ROWS  2048
#define D_IN    784
#define UNITS   128
#define D_OUT   10
#define RPB     8       // rows per block -> 256 blocks, rows 0..7 real in M=16
#define THREADS 512
#define NIT     10      // even (buffer parity: final read = buf 1, z0 -> buf 0)
#define ZSTR    138     // f16 Z row stride: 69 dwords = 5 mod 32
#define XSTR    788     // f32 Xs row stride: 20 mod 32 (=4*5, quads rotate)

typedef _Float16 f16x8 __attribute__((ext_vector_type(8)));
typedef float    f32x4 __attribute__((ext_vector_type(4)));

__device__ __forceinline__ float rcp_fast(float x) { return __builtin_amdgcn_rcpf(x); }

__device__ __forceinline__ float tanh_fast(float x) {
  float e = __expf(2.0f * x);
  return 1.0f - 2.0f * rcp_fast(e + 1.0f);
}

__device__ __forceinline__ f16x8 cvt8(f32x4 a, f32x4 b) {
  f16x8 r;
  r[0] = (_Float16)a[0]; r[1] = (_Float16)a[1]; r[2] = (_Float16)a[2]; r[3] = (_Float16)a[3];
  r[4] = (_Float16)b[0]; r[5] = (_Float16)b[1]; r[6] = (_Float16)b[2]; r[7] = (_Float16)b[3];
  return r;
}
__device__ __forceinline__ f16x8 res8(f32x4 a, f32x4 b, f16x8 hi) {
  f16x8 r;
  r[0] = (_Float16)(a[0] - (float)hi[0]); r[1] = (_Float16)(a[1] - (float)hi[1]);
  r[2] = (_Float16)(a[2] - (float)hi[2]); r[3] = (_Float16)(a[3] - (float)hi[3]);
  r[4] = (_Float16)(b[0] - (float)hi[4]); r[5] = (_Float16)(b[1] - (float)hi[5]);
  r[6] = (_Float16)(b[2] - (float)hi[6]); r[7] = (_Float16)(b[3] - (float)hi[7]);
  return r;
}

#define MFMA(a, b, c) __builtin_amdgcn_mfma_f32_16x16x32_f16((a), (b), (c), 0, 0, 0)

// Fragment conventions (validated R4-R9):
//   A: lane holds A[m=lo16][k = 32s + quad*8 + j], j=0..7
//   B: lane holds B[k = 32s + quad*8 + j][n=lo16]  (= Wrow[n][k..] row-major)
//   C/D: lane holds D[m = quad*4 + i][n=lo16], i=0..3

__global__ __launch_bounds__(THREADS, 2) void fused_net(
    const float* __restrict__ x,
    const float* __restrict__ W_in,
    const float* __restrict__ b_in,
    const float* __restrict__ W1,
    const float* __restrict__ W2,
    const float* __restrict__ W3,
    const float* __restrict__ W4,
    const float* __restrict__ W_out,
    const float* __restrict__ b_out,
    float* __restrict__ out)
{
  __shared__ __align__(16) _Float16 Zb[2][RPB][ZSTR];  // 8 real rows only
  __shared__ __align__(16) float    Xs[RPB][XSTR];     // staged x rows, padded
  __shared__ __align__(16) float    Wo[D_OUT * UNITS]; // staged W_out
  __shared__ float Bo[D_OUT];
  __shared__ __align__(16) float    Zh[RPB][132];      // final z4 for head
  __shared__ float Lg[RPB][D_OUT];

  const int t    = threadIdx.x;
  const int wave = t >> 6;        // 0..7, N-tile: units [16w, 16w+16)
  const int l    = t & 63;
  const int lo16 = l & 15;
  const int quad = l >> 4;
  const int u0   = wave * 16;
  const int r0   = blockIdx.x * RPB;

  const float bi = b_in[u0 + lo16];   // early scalar load

  const float* const Ws[4] = {W1, W2, W3, W4};

  // ---- prefetch W-frag raw data for wb=0 (consumed after input GEMM) ----
  f32x4 raw[8];
  {
    const float* a = Ws[0] + (size_t)(u0 + lo16) * UNITS;
#pragma unroll
    for (int s = 0; s < 4; ++s) {
      const int k = s * 32 + quad * 8;
      raw[s * 2]     = *(const f32x4*)(a + k);
      raw[s * 2 + 1] = *(const f32x4*)(a + k + 4);
    }
  }

  // ---- coalesced staging bursts (independent loads -> pipelined) ----
#pragma unroll 1
  for (int idx = t; idx < RPB * (D_IN / 4); idx += THREADS) {
    const int row = idx / (D_IN / 4);
    const int c4  = idx % (D_IN / 4);
    *(f32x4*)&Xs[row][c4 * 4] = *((const f32x4*)(x + (size_t)(r0 + row) * D_IN) + c4);
  }
  if (t < D_OUT * UNITS / 4)
    *((f32x4*)Wo + t) = *((const f32x4*)W_out + t);
  if (t < D_OUT) Bo[t] = b_out[t];
  __syncthreads();

  // ---- input GEMM: xf = x @ W_in.T + b_in (f16 hi/lo 3-term), x from LDS ----
  f32x4 acc = {0.f, 0.f, 0.f, 0.f};
  const float* wr = W_in + (size_t)(u0 + lo16) * D_IN;
  const float* xsrow = &Xs[lo16 & (RPB - 1)][0];
  // depth-2 prefetch of W_in (1 row/lane)
#define KCLAMP(s) (((s) * 32 + quad * 8 > 776) ? 776 : ((s) * 32 + quad * 8))
  f32x4 A0 = *(const f32x4*)(wr + KCLAMP(0));
  f32x4 A1 = *(const f32x4*)(wr + KCLAMP(0) + 4);
  f32x4 B0 = *(const f32x4*)(wr + KCLAMP(1));
  f32x4 B1 = *(const f32x4*)(wr + KCLAMP(1) + 4);
#pragma unroll 1
  for (int s = 0; s < 25; ++s) {
    f32x4 ca = A0, cb = A1;
    A0 = B0; A1 = B1;
    if (s + 2 < 25) {
      const int knc = KCLAMP(s + 2);
      B0 = *(const f32x4*)(wr + knc);
      B1 = *(const f32x4*)(wr + knc + 4);
    }
    const int k  = s * 32 + quad * 8;
    const int kc = KCLAMP(s);
    const bool act = ((k + 8) <= D_IN) && (lo16 < RPB);   // A rows RPB..15 zero
    f32x4 xa = *(const f32x4*)(xsrow + kc);
    f32x4 xb = *(const f32x4*)(xsrow + kc + 4);
    f16x8 ahi = cvt8(xa, xb);
    f16x8 alo = res8(xa, xb, ahi);
    if (!act) { ahi = (f16x8){}; alo = (f16x8){}; }
    f16x8 bh = cvt8(ca, cb);
    f16x8 bl = res8(ca, cb, bh);
    acc = MFMA(ahi, bh, acc);
    acc = MFMA(ahi, bl, acc);
    acc = MFMA(alo, bh, acc);
  }
  f32x4 xf;   // fixed-point input, f32, D-layout
#pragma unroll
  for (int i = 0; i < 4; ++i) xf[i] = acc[i] + bi;

  // masked A-frag read: only lanes with real rows touch LDS (exec-masked)
#define ZREAD(pbuf, off) \
  ((lo16 < RPB) ? *(const f16x8*)&Zb[pbuf][lo16 & (RPB - 1)][(off) + quad * 8] : (f16x8){})

  // ---- z0 for wb=0 ----
  if (quad < 2) {
#pragma unroll
    for (int i = 0; i < 4; ++i)
      Zb[0][quad * 4 + i][u0 + lo16] = (_Float16)tanh_fast(xf[i]);
  }
  __syncthreads();

  // ---- 4 implicit blocks: z = tanh(z @ W.T + xf), Picard ----
#pragma unroll 1
  for (int wb = 0; wb < 4; ++wb) {
    f16x8 wf[4];
#pragma unroll
    for (int s = 0; s < 4; ++s)
      wf[s] = cvt8(raw[s * 2], raw[s * 2 + 1]);
    if (wb < 3) {   // prefetch next W during this block's Picard loop
      const float* a = Ws[wb + 1] + (size_t)(u0 + lo16) * UNITS;
#pragma unroll
      for (int s = 0; s < 4; ++s) {
        const int k = s * 32 + quad * 8;
        raw[s * 2]     = *(const f32x4*)(a + k);
        raw[s * 2 + 1] = *(const f32x4*)(a + k + 4);
      }
    }

    int p = 0;
#pragma unroll 1
    for (int it = 0; it < NIT - 1; ++it) {        // 9 barrier rounds
      f16x8 a0 = ZREAD(p, 0);
      f16x8 a1 = ZREAD(p, 32);
      f16x8 a2 = ZREAD(p, 64);
      f16x8 a3 = ZREAD(p, 96);
      f32x4 c = xf;   // C = xf: "+x" free via the accumulator
      c = MFMA(a0, wf[0], c);
      c = MFMA(a1, wf[1], c);
      c = MFMA(a2, wf[2], c);
      c = MFMA(a3, wf[3], c);
      const int q = p ^ 1;
      if (quad < 2) {
#pragma unroll
        for (int i = 0; i < 4; ++i)
          Zb[q][quad * 4 + i][u0 + lo16] = (_Float16)tanh_fast(c[i]);
      }
      __syncthreads();
      p = q;
    }
    // final iteration (p == 1, NIT even): output = tanh(c) stays f32 in regs;
    // z0 of the NEXT block = tanh(tanh(c)) written here (merged z0 round).
    {
      f16x8 a0 = ZREAD(p, 0);
      f16x8 a1 = ZREAD(p, 32);
      f16x8 a2 = ZREAD(p, 64);
      f16x8 a3 = ZREAD(p, 96);
      f32x4 c = xf;
      c = MFMA(a0, wf[0], c);
      c = MFMA(a1, wf[1], c);
      c = MFMA(a2, wf[2], c);
      c = MFMA(a3, wf[3], c);
#pragma unroll
      for (int i = 0; i < 4; ++i) xf[i] = tanh_fast(c[i]);
      if (wb < 3) {
        // buf 0's last readers passed the it=NIT-2 barrier; write is race-free
        if (quad < 2) {
#pragma unroll
          for (int i = 0; i < 4; ++i)
            Zb[0][quad * 4 + i][u0 + lo16] = (_Float16)tanh_fast(xf[i]);
        }
        __syncthreads();   // separates buf-1 final reads from next wb's buf-1 writes
      }
    }
  }

  // ---- head: logits = z4 @ W_out.T + b_out, softmax ----
  if (quad < 2) {
#pragma unroll
    for (int i = 0; i < 4; ++i)
      Zh[quad * 4 + i][u0 + lo16] = xf[i];
  }
  __syncthreads();

  if (t < RPB * D_OUT) {
    const int r = t / D_OUT, c = t % D_OUT;
    float s = Bo[c];
    const float* wo = &Wo[c * UNITS];
#pragma unroll
    for (int k = 0; k < UNITS; k += 4) {
      f32x4 zv = *(const f32x4*)&Zh[r][k];
      f32x4 wv = *(const f32x4*)&wo[k];
      s = fmaf(zv[0], wv[0], s);
      s = fmaf(zv[1], wv[1], s);
      s = fmaf(zv[2], wv[2], s);
      s = fmaf(zv[3], wv[3], s);
    }
    Lg[r][c] = s;
  }
  __syncthreads();
  if (t < RPB) {
    float m = Lg[t][0];
#pragma unroll
    for (int c = 1; c < D_OUT; ++c) m = fmaxf(m, Lg[t][c]);
    float e[D_OUT];
    float sum = 0.f;
#pragma unroll
    for (int c = 0; c < D_OUT; ++c) { e[c] = __expf(Lg[t][c] - m); sum += e[c]; }
    const float rs = rcp_fast(sum);
    float* orow = out + (size_t)(r0 + t) * D_OUT;
#pragma unroll
    for (int c = 0; c < D_OUT; ++c) orow[c] = e[c] * rs;
  }
}

extern "C" void kernel_launch(void* const* d_in, const int* in_sizes, int n_in,
                              void* d_out, int out_size, void* d_ws, size_t ws_size,
                              hipStream_t stream) {
  const float* x     = (const float*)d_in[0];
  const float* W_in  = (const float*)d_in[1];
  const float* b_in  = (const float*)d_in[2];
  const float* W1    = (const float*)d_in[3];
  const float* W2    = (const float*)d_in[4];
  const float* W3    = (const float*)d_in[5];
  const float* W4    = (const float*)d_in[6];
  const float* W_out = (const float*)d_in[7];
  const float* b_out = (const float*)d_in[8];
  float* outp = (float*)d_out;

  dim3 grid(B_ROWS / RPB);      // 256 blocks x 8 waves, full chip
  dim3 block(THREADS);
  hipLaunchKernelGGL(fused_net, grid, block, 0, stream,
                     x, W_in, b_in, W1, W2, W3, W4, W_out, b_out, outp);
}

// Round 11
// 103.681 us; speedup vs baseline: 1.1534x; 1.0201x over previous
//
#include <hip/hip_runtime.h>

// NewtonImplicitNet via Picard iteration, MFMA, slim edition.
// R10 post-mortem: per-round wall ~1700 cyc is serial-chain latency (tanh +
// write-drain + barrier skew + LDS read + MFMA chain); round count and bank
// conflicts were NOT the limiter; prologue ~10us of the 43.5.
// R11: (1) NIT 10->8 (absmax pinned at f16 floor 9.77e-4 from NIT 20..10 ->
// residual far below noise; 40->32 rounds); (2) no LDS staging: x direct
// from global (L1 broadcast across waves; kills the staging drain barrier),
// depth-2 prefetch on x and W_in, input GEMM 2-term hi/lo (x exact, W f16);
// (3) head via MFMA (z4 f16 through Zb, wave 0: 4 mfma + shfl-16 softmax).

#define B_ROWS  2048
#define D_IN    784
#define UNITS   128
#define D_OUT   10
#define RPB     8       // rows per block -> 256 blocks, rows 0..7 real in M=16
#define THREADS 512
#define NIT     8       // even (buffer parity: final read = buf 1, z0 -> buf 0)
#define ZSTR    138     // f16 Z row stride: 69 dwords = 5 mod 32 (2-way max)

typedef _Float16 f16x8 __attribute__((ext_vector_type(8)));
typedef float    f32x4 __attribute__((ext_vector_type(4)));

__device__ __forceinline__ float rcp_fast(float x) { return __builtin_amdgcn_rcpf(x); }

__device__ __forceinline__ float tanh_fast(float x) {
  float e = __expf(2.0f * x);
  return 1.0f - 2.0f * rcp_fast(e + 1.0f);
}

__device__ __forceinline__ f16x8 cvt8(f32x4 a, f32x4 b) {
  f16x8 r;
  r[0] = (_Float16)a[0]; r[1] = (_Float16)a[1]; r[2] = (_Float16)a[2]; r[3] = (_Float16)a[3];
  r[4] = (_Float16)b[0]; r[5] = (_Float16)b[1]; r[6] = (_Float16)b[2]; r[7] = (_Float16)b[3];
  return r;
}
__device__ __forceinline__ f16x8 res8(f32x4 a, f32x4 b, f16x8 hi) {
  f16x8 r;
  r[0] = (_Float16)(a[0] - (float)hi[0]); r[1] = (_Float16)(a[1] - (float)hi[1]);
  r[2] = (_Float16)(a[2] - (float)hi[2]); r[3] = (_Float16)(a[3] - (float)hi[3]);
  r[4] = (_Float16)(b[0] - (float)hi[4]); r[5] = (_Float16)(b[1] - (float)hi[5]);
  r[6] = (_Float16)(b[2] - (float)hi[6]); r[7] = (_Float16)(b[3] - (float)hi[7]);
  return r;
}

#define MFMA(a, b, c) __builtin_amdgcn_mfma_f32_16x16x32_f16((a), (b), (c), 0, 0, 0)

// Fragment conventions (validated R4-R10):
//   A: lane holds A[m=lo16][k = 32s + quad*8 + j], j=0..7
//   B: lane holds B[k = 32s + quad*8 + j][n=lo16]  (= Wrow[n][k..] row-major)
//   C/D: lane holds D[m = quad*4 + i][n=lo16], i=0..3

__global__ __launch_bounds__(THREADS, 2) void fused_net(
    const float* __restrict__ x,
    const float* __restrict__ W_in,
    const float* __restrict__ b_in,
    const float* __restrict__ W1,
    const float* __restrict__ W2,
    const float* __restrict__ W3,
    const float* __restrict__ W4,
    const float* __restrict__ W_out,
    const float* __restrict__ b_out,
    float* __restrict__ out)
{
  __shared__ __align__(16) _Float16 Zb[2][RPB][ZSTR];  // the only LDS (~4.4 KB)

  const int t    = threadIdx.x;
  const int wave = t >> 6;        // 0..7, N-tile: units [16w, 16w+16)
  const int l    = t & 63;
  const int lo16 = l & 15;
  const int quad = l >> 4;
  const int u0   = wave * 16;
  const int r0   = blockIdx.x * RPB;

  const float bi = b_in[u0 + lo16];   // early scalar load

  const float* const Ws[4] = {W1, W2, W3, W4};

  // ---- prefetch W-frag raw data for wb=0 (consumed after input GEMM) ----
  f32x4 raw[8];
  {
    const float* a = Ws[0] + (size_t)(u0 + lo16) * UNITS;
#pragma unroll
    for (int s = 0; s < 4; ++s) {
      const int k = s * 32 + quad * 8;
      raw[s * 2]     = *(const f32x4*)(a + k);
      raw[s * 2 + 1] = *(const f32x4*)(a + k + 4);
    }
  }

  // ---- input GEMM: xf = x @ W_in.T + b_in (2-term: x split hi/lo @ W f16) ----
  // x read direct from global: 8 distinct rows, duplicated across quads and
  // waves -> L1 broadcast after first touch. No staging barrier.
#define KCLAMP(s) (((s) * 32 + quad * 8 > 776) ? 776 : ((s) * 32 + quad * 8))
  f32x4 acc = {0.f, 0.f, 0.f, 0.f};
  const float* xr = x    + (size_t)(r0 + (lo16 & 7)) * D_IN;
  const float* wr = W_in + (size_t)(u0 + lo16) * D_IN;
  f32x4 XA0 = *(const f32x4*)(xr + KCLAMP(0));
  f32x4 XA1 = *(const f32x4*)(xr + KCLAMP(0) + 4);
  f32x4 WA0 = *(const f32x4*)(wr + KCLAMP(0));
  f32x4 WA1 = *(const f32x4*)(wr + KCLAMP(0) + 4);
  f32x4 XB0 = *(const f32x4*)(xr + KCLAMP(1));
  f32x4 XB1 = *(const f32x4*)(xr + KCLAMP(1) + 4);
  f32x4 WB0 = *(const f32x4*)(wr + KCLAMP(1));
  f32x4 WB1 = *(const f32x4*)(wr + KCLAMP(1) + 4);
#pragma unroll 1
  for (int s = 0; s < 25; ++s) {
    f32x4 xa = XA0, xb = XA1, wa = WA0, wb2 = WA1;
    XA0 = XB0; XA1 = XB1; WA0 = WB0; WA1 = WB1;
    if (s + 2 < 25) {
      const int knc = KCLAMP(s + 2);
      XB0 = *(const f32x4*)(xr + knc);  XB1 = *(const f32x4*)(xr + knc + 4);
      WB0 = *(const f32x4*)(wr + knc);  WB1 = *(const f32x4*)(wr + knc + 4);
    }
    const int k = s * 32 + quad * 8;
    const bool act = ((k + 8) <= D_IN) && (lo16 < RPB);   // A rows RPB..15 zero
    f16x8 ahi = cvt8(xa, xb);
    f16x8 alo = res8(xa, xb, ahi);
    if (!act) { ahi = (f16x8){}; alo = (f16x8){}; }
    f16x8 bh = cvt8(wa, wb2);
    acc = MFMA(ahi, bh, acc);
    acc = MFMA(alo, bh, acc);      // x exact (hi+lo), W rounded once (~5e-4)
  }
  f32x4 xf;   // fixed-point input, f32, D-layout
#pragma unroll
  for (int i = 0; i < 4; ++i) xf[i] = acc[i] + bi;

  // masked A-frag read: only lanes with real rows touch LDS (exec-masked)
#define ZREAD(pbuf, off) \
  ((lo16 < RPB) ? *(const f16x8*)&Zb[pbuf][lo16 & (RPB - 1)][(off) + quad * 8] : (f16x8){})

  // ---- z0 for wb=0 ----
  if (quad < 2) {
#pragma unroll
    for (int i = 0; i < 4; ++i)
      Zb[0][quad * 4 + i][u0 + lo16] = (_Float16)tanh_fast(xf[i]);
  }
  __syncthreads();

  // ---- 4 implicit blocks: z = tanh(z @ W.T + xf), Picard ----
#pragma unroll 1
  for (int wb = 0; wb < 4; ++wb) {
    f16x8 wf[4];
#pragma unroll
    for (int s = 0; s < 4; ++s)
      wf[s] = cvt8(raw[s * 2], raw[s * 2 + 1]);
    if (wb < 3) {   // prefetch next W during this block's Picard loop
      const float* a = Ws[wb + 1] + (size_t)(u0 + lo16) * UNITS;
#pragma unroll
      for (int s = 0; s < 4; ++s) {
        const int k = s * 32 + quad * 8;
        raw[s * 2]     = *(const f32x4*)(a + k);
        raw[s * 2 + 1] = *(const f32x4*)(a + k + 4);
      }
    }

    int p = 0;
#pragma unroll 1
    for (int it = 0; it < NIT - 1; ++it) {        // 7 barrier rounds
      f16x8 a0 = ZREAD(p, 0);
      f16x8 a1 = ZREAD(p, 32);
      f16x8 a2 = ZREAD(p, 64);
      f16x8 a3 = ZREAD(p, 96);
      f32x4 c = xf;   // C = xf: "+x" free via the accumulator
      c = MFMA(a0, wf[0], c);
      c = MFMA(a1, wf[1], c);
      c = MFMA(a2, wf[2], c);
      c = MFMA(a3, wf[3], c);
      const int q = p ^ 1;
      if (quad < 2) {
#pragma unroll
        for (int i = 0; i < 4; ++i)
          Zb[q][quad * 4 + i][u0 + lo16] = (_Float16)tanh_fast(c[i]);
      }
      __syncthreads();
      p = q;
    }
    // final iteration (p == 1): output = tanh(c) stays f32 in regs -> next xf.
    // wb<3: write z0 of next block = tanh(xf'). wb==3: write z4 itself (head).
    {
      f16x8 a0 = ZREAD(p, 0);
      f16x8 a1 = ZREAD(p, 32);
      f16x8 a2 = ZREAD(p, 64);
      f16x8 a3 = ZREAD(p, 96);
      f32x4 c = xf;
      c = MFMA(a0, wf[0], c);
      c = MFMA(a1, wf[1], c);
      c = MFMA(a2, wf[2], c);
      c = MFMA(a3, wf[3], c);
#pragma unroll
      for (int i = 0; i < 4; ++i) xf[i] = tanh_fast(c[i]);
      // buf 0's last readers passed the it=NIT-2 barrier -> write race-free
      if (quad < 2) {
#pragma unroll
        for (int i = 0; i < 4; ++i)
          Zb[0][quad * 4 + i][u0 + lo16] =
              (_Float16)((wb < 3) ? tanh_fast(xf[i]) : xf[i]);
      }
      __syncthreads();
    }
  }

  // ---- head (wave 0 only): logits = z4 @ W_out.T + b_out via MFMA, softmax ----
  if (wave == 0) {
    const int cls = (lo16 < D_OUT) ? lo16 : 0;
    const float* wo = W_out + (size_t)cls * UNITS;
    f16x8 bf[4];
#pragma unroll
    for (int s = 0; s < 4; ++s) {
      const int k = s * 32 + quad * 8;
      bf[s] = cvt8(*(const f32x4*)(wo + k), *(const f32x4*)(wo + k + 4));
      if (lo16 >= D_OUT) bf[s] = (f16x8){};
    }
    const float bo = b_out[cls];
    f16x8 a0 = ZREAD(0, 0);
    f16x8 a1 = ZREAD(0, 32);
    f16x8 a2 = ZREAD(0, 64);
    f16x8 a3 = ZREAD(0, 96);
    f32x4 c = {0.f, 0.f, 0.f, 0.f};
    c = MFMA(a0, bf[0], c);
    c = MFMA(a1, bf[1], c);
    c = MFMA(a2, bf[2], c);
    c = MFMA(a3, bf[3], c);
    // D[m=quad*4+i][n=lo16]: rows 0..7 real (quads 0,1), classes lo16<10
    float pr[4];
#pragma unroll
    for (int i = 0; i < 4; ++i) {
      float v = (lo16 < D_OUT) ? (c[i] + bo) : -1e30f;
      float m = v;
#pragma unroll
      for (int d = 1; d < 16; d <<= 1) m = fmaxf(m, __shfl_xor(m, d, 16));
      float e = (lo16 < D_OUT) ? __expf(v - m) : 0.f;
      float sm = e;
#pragma unroll
      for (int d = 1; d < 16; d <<= 1) sm += __shfl_xor(sm, d, 16);
      pr[i] = e * rcp_fast(sm);
    }
    if (quad < 2 && lo16 < D_OUT) {
#pragma unroll
      for (int i = 0; i < 4; ++i)
        out[(size_t)(r0 + quad * 4 + i) * D_OUT + lo16] = pr[i];
    }
  }
}

extern "C" void kernel_launch(void* const* d_in, const int* in_sizes, int n_in,
                              void* d_out, int out_size, void* d_ws, size_t ws_size,
                              hipStream_t stream) {
  const float* x     = (const float*)d_in[0];
  const float* W_in  = (const float*)d_in[1];
  const float* b_in  = (const float*)d_in[2];
  const float* W1    = (const float*)d_in[3];
  const float* W2    = (const float*)d_in[4];
  const float* W3    = (const float*)d_in[5];
  const float* W4    = (const float*)d_in[6];
  const float* W_out = (const float*)d_in[7];
  const float* b_out = (const float*)d_in[8];
  float* outp = (float*)d_out;

  dim3 grid(B_ROWS / RPB);      // 256 blocks x 8 waves, full chip
  dim3 block(THREADS);
  hipLaunchKernelGGL(fused_net, grid, block, 0, stream,
                     x, W_in, b_in, W1, W2, W3, W4, W_out, b_out, outp);
}

// Round 12
// 101.064 us; speedup vs baseline: 1.1833x; 1.0259x over previous
//
#include <hip/hip_runtime.h>

// NewtonImplicitNet via Picard iteration, MFMA, shaved edition.
// R11 post-mortem: dispatch ~40us; per-CU LDS pipe (~700 cyc/round: 32
// ds_read_b128 + 64 ds_write_b16) is ~half the round wall; rounds fixed at
// 32 by accuracy (NIT=8 -> 1.95e-3; NIT=6 risks the 7.8e-3 threshold).
// R12 shavings: (1) A-rows 8-15 may be GARBAGE (MFMA row-separable, D rows
// 8-15 never read) -> unconditional A-frag reads, no cndmask row-masking
// anywhere; k-pad mask hoisted to an s=24 epilogue; (2) depth-4 prefetch
// ring in the input GEMM (unroll 4); (3) MFMA chain split 2+2 (+f32 add);
// (4) Picard inner loop fully unrolled (static buffer parity).

#define B_ROWS  2048
#define D_IN    784
#define UNITS   128
#define D_OUT   10
#define RPB     8       // rows per block -> 256 blocks, rows 0..7 real in M=16
#define THREADS 512
#define NIT     8       // even (buffer parity: final read = buf 1, z0 -> buf 0)
#define ZSTR    138     // f16 Z row stride: 69 dwords = 5 mod 32 (2-way max)

typedef _Float16 f16x8 __attribute__((ext_vector_type(8)));
typedef float    f32x4 __attribute__((ext_vector_type(4)));

__device__ __forceinline__ float rcp_fast(float x) { return __builtin_amdgcn_rcpf(x); }

__device__ __forceinline__ float tanh_fast(float x) {
  float e = __expf(2.0f * x);
  return 1.0f - 2.0f * rcp_fast(e + 1.0f);
}

__device__ __forceinline__ f16x8 cvt8(f32x4 a, f32x4 b) {
  f16x8 r;
  r[0] = (_Float16)a[0]; r[1] = (_Float16)a[1]; r[2] = (_Float16)a[2]; r[3] = (_Float16)a[3];
  r[4] = (_Float16)b[0]; r[5] = (_Float16)b[1]; r[6] = (_Float16)b[2]; r[7] = (_Float16)b[3];
  return r;
}
__device__ __forceinline__ f16x8 res8(f32x4 a, f32x4 b, f16x8 hi) {
  f16x8 r;
  r[0] = (_Float16)(a[0] - (float)hi[0]); r[1] = (_Float16)(a[1] - (float)hi[1]);
  r[2] = (_Float16)(a[2] - (float)hi[2]); r[3] = (_Float16)(a[3] - (float)hi[3]);
  r[4] = (_Float16)(b[0] - (float)hi[4]); r[5] = (_Float16)(b[1] - (float)hi[5]);
  r[6] = (_Float16)(b[2] - (float)hi[6]); r[7] = (_Float16)(b[7-7] - (float)hi[6]);
  // (line above replaced below - kept simple)
  r[6] = (_Float16)(b[2] - (float)hi[6]);
  r[7] = (_Float16)(b[3] - (float)hi[7]);
  return r;
}

#define MFMA(a, b, c) __builtin_amdgcn_mfma_f32_16x16x32_f16((a), (b), (c), 0, 0, 0)

// Fragment conventions (validated R4-R11):
//   A: lane holds A[m=lo16][k = 32s + quad*8 + j], j=0..7
//   B: lane holds B[k = 32s + quad*8 + j][n=lo16]  (= Wrow[n][k..] row-major)
//   C/D: lane holds D[m = quad*4 + i][n=lo16], i=0..3
// D rows depend only on A rows -> A rows 8..15 may hold garbage (dup of 0..7).

__global__ __launch_bounds__(THREADS, 1) void fused_net(
    const float* __restrict__ x,
    const float* __restrict__ W_in,
    const float* __restrict__ b_in,
    const float* __restrict__ W1,
    const float* __restrict__ W2,
    const float* __restrict__ W3,
    const float* __restrict__ W4,
    const float* __restrict__ W_out,
    const float* __restrict__ b_out,
    float* __restrict__ out)
{
  __shared__ __align__(16) _Float16 Zb[2][RPB][ZSTR];  // the only LDS (~4.4 KB)

  const int t    = threadIdx.x;
  const int wave = t >> 6;        // 0..7, N-tile: units [16w, 16w+16)
  const int l    = t & 63;
  const int lo16 = l & 15;
  const int quad = l >> 4;
  const int u0   = wave * 16;
  const int r0   = blockIdx.x * RPB;

  const float bi = b_in[u0 + lo16];   // early scalar load

  const float* const Ws[4] = {W1, W2, W3, W4};

  // ---- prefetch W-frag raw data for wb=0 (consumed after input GEMM) ----
  f32x4 raw[8];
  {
    const float* a = Ws[0] + (size_t)(u0 + lo16) * UNITS;
#pragma unroll
    for (int s = 0; s < 4; ++s) {
      const int k = s * 32 + quad * 8;
      raw[s * 2]     = *(const f32x4*)(a + k);
      raw[s * 2 + 1] = *(const f32x4*)(a + k + 4);
    }
  }

  // ---- input GEMM: xf = x @ W_in.T + b_in (2-term: x hi/lo @ W f16) ----
  // Rows: lane lo16&7 -> rows 8..15 duplicate rows 0..7 (garbage D rows, OK).
  // s = 0..23 fully valid (k+8 <= 768+24 <= 784); s=24 masked epilogue.
  f32x4 acc  = {0.f, 0.f, 0.f, 0.f};
  f32x4 acc2 = {0.f, 0.f, 0.f, 0.f};
  const float* xr = x    + (size_t)(r0 + (lo16 & 7)) * D_IN;
  const float* wr = W_in + (size_t)(u0 + lo16) * D_IN;
  f32x4 XB[4][2], WB[4][2];   // depth-4 prefetch ring
#pragma unroll
  for (int j = 0; j < 4; ++j) {
    const int k = j * 32 + quad * 8;
    XB[j][0] = *(const f32x4*)(xr + k);  XB[j][1] = *(const f32x4*)(xr + k + 4);
    WB[j][0] = *(const f32x4*)(wr + k);  WB[j][1] = *(const f32x4*)(wr + k + 4);
  }
#pragma unroll 4
  for (int s = 0; s < 24; ++s) {
    f32x4 xa = XB[s & 3][0], xb = XB[s & 3][1];
    f32x4 wa = WB[s & 3][0], wb2 = WB[s & 3][1];
    if (s + 4 <= 24) {   // prefetch stage s+4 (stage 24 clamped below)
      const int kn = (s + 4) * 32 + quad * 8;
      const int kc = (kn > 776) ? 776 : kn;
      XB[s & 3][0] = *(const f32x4*)(xr + kc);  XB[s & 3][1] = *(const f32x4*)(xr + kc + 4);
      WB[s & 3][0] = *(const f32x4*)(wr + kc);  WB[s & 3][1] = *(const f32x4*)(wr + kc + 4);
    }
    f16x8 ahi = cvt8(xa, xb);
    f16x8 alo = res8(xa, xb, ahi);
    f16x8 bh  = cvt8(wa, wb2);
    acc  = MFMA(ahi, bh, acc);
    acc2 = MFMA(alo, bh, acc2);   // two independent chains
  }
  {   // s = 24: k = 768 + quad*8; quads 2,3 out of range -> zero A
    f32x4 xa = XB[0][0], xb = XB[0][1];
    f32x4 wa = WB[0][0], wb2 = WB[0][1];
    f16x8 ahi = cvt8(xa, xb);
    f16x8 alo = res8(xa, xb, ahi);
    if (quad >= 2) { ahi = (f16x8){}; alo = (f16x8){}; }  // wave-uniform per quad
    f16x8 bh = cvt8(wa, wb2);
    acc  = MFMA(ahi, bh, acc);
    acc2 = MFMA(alo, bh, acc2);
  }
  f32x4 xf;   // fixed-point input, f32, D-layout
#pragma unroll
  for (int i = 0; i < 4; ++i) xf[i] = acc[i] + acc2[i] + bi;

  // unconditional A-frag read: rows 8..15 duplicate rows 0..7 (garbage-OK)
#define ZREAD(pbuf, off) (*(const f16x8*)&Zb[pbuf][lo16 & 7][(off) + quad * 8])

  // ---- z0 for wb=0 ----
  if (quad < 2) {
#pragma unroll
    for (int i = 0; i < 4; ++i)
      Zb[0][quad * 4 + i][u0 + lo16] = (_Float16)tanh_fast(xf[i]);
  }
  __syncthreads();

  // ---- 4 implicit blocks: z = tanh(z @ W.T + xf), Picard ----
#pragma unroll 1
  for (int wb = 0; wb < 4; ++wb) {
    f16x8 wf[4];
#pragma unroll
    for (int s = 0; s < 4; ++s)
      wf[s] = cvt8(raw[s * 2], raw[s * 2 + 1]);
    if (wb < 3) {   // prefetch next W during this block's Picard loop
      const float* a = Ws[wb + 1] + (size_t)(u0 + lo16) * UNITS;
#pragma unroll
      for (int s = 0; s < 4; ++s) {
        const int k = s * 32 + quad * 8;
        raw[s * 2]     = *(const f32x4*)(a + k);
        raw[s * 2 + 1] = *(const f32x4*)(a + k + 4);
      }
    }

#pragma unroll
    for (int it = 0; it < NIT - 1; ++it) {        // 7 rounds, p static
      const int p = it & 1;
      f16x8 a0 = ZREAD(p, 0);
      f16x8 a1 = ZREAD(p, 32);
      f16x8 a2 = ZREAD(p, 64);
      f16x8 a3 = ZREAD(p, 96);
      f32x4 chi = xf;                         // chain 1: xf + A0W0 + A1W1
      f32x4 clo = {0.f, 0.f, 0.f, 0.f};       // chain 2: A2W2 + A3W3
      chi = MFMA(a0, wf[0], chi);
      clo = MFMA(a2, wf[2], clo);
      chi = MFMA(a1, wf[1], chi);
      clo = MFMA(a3, wf[3], clo);
      const int q = p ^ 1;
      if (quad < 2) {
#pragma unroll
        for (int i = 0; i < 4; ++i)
          Zb[q][quad * 4 + i][u0 + lo16] = (_Float16)tanh_fast(chi[i] + clo[i]);
      }
      __syncthreads();
    }
    // final iteration (reads buf 1): output = tanh(c) stays f32 -> next xf.
    // wb<3: write z0 of next block = tanh(xf'); wb==3: write z4 itself (head).
    {
      f16x8 a0 = ZREAD(1, 0);
      f16x8 a1 = ZREAD(1, 32);
      f16x8 a2 = ZREAD(1, 64);
      f16x8 a3 = ZREAD(1, 96);
      f32x4 chi = xf;
      f32x4 clo = {0.f, 0.f, 0.f, 0.f};
      chi = MFMA(a0, wf[0], chi);
      clo = MFMA(a2, wf[2], clo);
      chi = MFMA(a1, wf[1], chi);
      clo = MFMA(a3, wf[3], clo);
#pragma unroll
      for (int i = 0; i < 4; ++i) xf[i] = tanh_fast(chi[i] + clo[i]);
      // buf 0's last readers passed the it=NIT-2 barrier -> write race-free
      if (quad < 2) {
#pragma unroll
        for (int i = 0; i < 4; ++i)
          Zb[0][quad * 4 + i][u0 + lo16] =
              (_Float16)((wb < 3) ? tanh_fast(xf[i]) : xf[i]);
      }
      __syncthreads();
    }
  }

  // ---- head (wave 0 only): logits = z4 @ W_out.T + b_out via MFMA, softmax ----
  if (wave == 0) {
    const int cls = (lo16 < D_OUT) ? lo16 : 0;
    const float* wo = W_out + (size_t)cls * UNITS;
    f16x8 bf[4];
#pragma unroll
    for (int s = 0; s < 4; ++s) {
      const int k = s * 32 + quad * 8;
      bf[s] = cvt8(*(const f32x4*)(wo + k), *(const f32x4*)(wo + k + 4));
      if (lo16 >= D_OUT) bf[s] = (f16x8){};
    }
    const float bo = b_out[cls];
    f16x8 a0 = ZREAD(0, 0);
    f16x8 a1 = ZREAD(0, 32);
    f16x8 a2 = ZREAD(0, 64);
    f16x8 a3 = ZREAD(0, 96);
    f32x4 c = {0.f, 0.f, 0.f, 0.f};
    c = MFMA(a0, bf[0], c);
    c = MFMA(a1, bf[1], c);
    c = MFMA(a2, bf[2], c);
    c = MFMA(a3, bf[3], c);
    // D[m=quad*4+i][n=lo16]: rows 0..7 real (quads 0,1), classes lo16<10
    float pr[4];
#pragma unroll
    for (int i = 0; i < 4; ++i) {
      float v = (lo16 < D_OUT) ? (c[i] + bo) : -1e30f;
      float m = v;
#pragma unroll
      for (int d = 1; d < 16; d <<= 1) m = fmaxf(m, __shfl_xor(m, d, 16));
      float e = (lo16 < D_OUT) ? __expf(v - m) : 0.f;
      float sm = e;
#pragma unroll
      for (int d = 1; d < 16; d <<= 1) sm += __shfl_xor(sm, d, 16);
      pr[i] = e * rcp_fast(sm);
    }
    if (quad < 2 && lo16 < D_OUT) {
#pragma unroll
      for (int i = 0; i < 4; ++i)
        out[(size_t)(r0 + quad * 4 + i) * D_OUT + lo16] = pr[i];
    }
  }
}

extern "C" void kernel_launch(void* const* d_in, const int* in_sizes, int n_in,
                              void* d_out, int out_size, void* d_ws, size_t ws_size,
                              hipStream_t stream) {
  const float* x     = (const float*)d_in[0];
  const float* W_in  = (const float*)d_in[1];
  const float* b_in  = (const float*)d_in[2];
  const float* W1    = (const float*)d_in[3];
  const float* W2    = (const float*)d_in[4];
  const float* W3    = (const float*)d_in[5];
  const float* W4    = (const float*)d_in[6];
  const float* W_out = (const float*)d_in[7];
  const float* b_out = (const float*)d_in[8];
  float* outp = (float*)d_out;

  dim3 grid(B_ROWS / RPB);      // 256 blocks x 8 waves, full chip
  dim3 block(THREADS);
  hipLaunchKernelGGL(fused_net, grid, block, 0, stream,
                     x, W_in, b_in, W1, W2, W3, W4, W_out, b_out, outp);
}

// Round 13
// 99.148 us; speedup vs baseline: 1.2062x; 1.0193x over previous
//
#include <hip/hip_runtime.h>

// NewtonImplicitNet via Picard iteration, MFMA, 28-round edition.
// R12 post-mortem: dispatch ~38us; per-round wall ~1100 cyc is chain latency
// (barrier skew + LDS turnaround + MFMA/tanh); LDS instr count per wave is
// already minimal (4x b128 read floor; b16 scatter writes can't pack without
// doubling reads). Rounds are the remaining lever.
// R13: NIT 8->7 (32->28 rounds). Accuracy: absmax 9.77e-4(NIT>=10, f16
// floor) -> 1.95e-3(NIT=8); one fewer iter multiplies residual by 1/rho~2-3
// -> predicted 3.9e-3 < 7.8e-3 threshold. Odd NIT via alternating buffer
// parity s_wb = wb&1 (7 rounds flip parity per block): final iter reads buf
// s_wb, writes next-z0 to s_wb^1 (last read at it=5, barrier passed) -- no
// extra barrier; wb=3's z4 lands in buf 0 where the head reads. wb loop
// fully unrolled so parities constant-fold.

#define B_ROWS  2048
#define D_IN    784
#define UNITS   128
#define D_OUT   10
#define RPB     8       // rows per block -> 256 blocks, rows 0..7 real in M=16
#define THREADS 512
#define NIT     7       // odd: per-wb parity alternates (s_wb = wb&1)
#define ZSTR    138     // f16 Z row stride: 69 dwords = 5 mod 32 (2-way max)

typedef _Float16 f16x8 __attribute__((ext_vector_type(8)));
typedef float    f32x4 __attribute__((ext_vector_type(4)));

__device__ __forceinline__ float rcp_fast(float x) { return __builtin_amdgcn_rcpf(x); }

__device__ __forceinline__ float tanh_fast(float x) {
  float e = __expf(2.0f * x);
  return 1.0f - 2.0f * rcp_fast(e + 1.0f);
}

__device__ __forceinline__ f16x8 cvt8(f32x4 a, f32x4 b) {
  f16x8 r;
  r[0] = (_Float16)a[0]; r[1] = (_Float16)a[1]; r[2] = (_Float16)a[2]; r[3] = (_Float16)a[3];
  r[4] = (_Float16)b[0]; r[5] = (_Float16)b[1]; r[6] = (_Float16)b[2]; r[7] = (_Float16)b[3];
  return r;
}
__device__ __forceinline__ f16x8 res8(f32x4 a, f32x4 b, f16x8 hi) {
  f16x8 r;
  r[0] = (_Float16)(a[0] - (float)hi[0]); r[1] = (_Float16)(a[1] - (float)hi[1]);
  r[2] = (_Float16)(a[2] - (float)hi[2]); r[3] = (_Float16)(a[3] - (float)hi[3]);
  r[4] = (_Float16)(b[0] - (float)hi[4]); r[5] = (_Float16)(b[1] - (float)hi[5]);
  r[6] = (_Float16)(b[2] - (float)hi[6]); r[7] = (_Float16)(b[3] - (float)hi[7]);
  return r;
}

#define MFMA(a, b, c) __builtin_amdgcn_mfma_f32_16x16x32_f16((a), (b), (c), 0, 0, 0)

// Fragment conventions (validated R4-R12):
//   A: lane holds A[m=lo16][k = 32s + quad*8 + j], j=0..7
//   B: lane holds B[k = 32s + quad*8 + j][n=lo16]  (= Wrow[n][k..] row-major)
//   C/D: lane holds D[m = quad*4 + i][n=lo16], i=0..3
// D rows depend only on A rows -> A rows 8..15 may hold garbage (dup of 0..7).

__global__ __launch_bounds__(THREADS, 1) void fused_net(
    const float* __restrict__ x,
    const float* __restrict__ W_in,
    const float* __restrict__ b_in,
    const float* __restrict__ W1,
    const float* __restrict__ W2,
    const float* __restrict__ W3,
    const float* __restrict__ W4,
    const float* __restrict__ W_out,
    const float* __restrict__ b_out,
    float* __restrict__ out)
{
  __shared__ __align__(16) _Float16 Zb[2][RPB][ZSTR];  // the only LDS (~4.4 KB)

  const int t    = threadIdx.x;
  const int wave = t >> 6;        // 0..7, N-tile: units [16w, 16w+16)
  const int l    = t & 63;
  const int lo16 = l & 15;
  const int quad = l >> 4;
  const int u0   = wave * 16;
  const int r0   = blockIdx.x * RPB;

  const float bi = b_in[u0 + lo16];   // early scalar load

  const float* const Ws[4] = {W1, W2, W3, W4};

  // ---- prefetch W-frag raw data for wb=0 (consumed after input GEMM) ----
  f32x4 raw[8];
  {
    const float* a = Ws[0] + (size_t)(u0 + lo16) * UNITS;
#pragma unroll
    for (int s = 0; s < 4; ++s) {
      const int k = s * 32 + quad * 8;
      raw[s * 2]     = *(const f32x4*)(a + k);
      raw[s * 2 + 1] = *(const f32x4*)(a + k + 4);
    }
  }

  // ---- input GEMM: xf = x @ W_in.T + b_in (2-term: x hi/lo @ W f16) ----
  // Rows: lane lo16&7 -> rows 8..15 duplicate rows 0..7 (garbage D rows, OK).
  // s = 0..23 fully valid; s=24 masked epilogue (quads 2,3 out of range).
  f32x4 acc  = {0.f, 0.f, 0.f, 0.f};
  f32x4 acc2 = {0.f, 0.f, 0.f, 0.f};
  const float* xr = x    + (size_t)(r0 + (lo16 & 7)) * D_IN;
  const float* wr = W_in + (size_t)(u0 + lo16) * D_IN;
  f32x4 XB[4][2], WB[4][2];   // depth-4 prefetch ring
#pragma unroll
  for (int j = 0; j < 4; ++j) {
    const int k = j * 32 + quad * 8;
    XB[j][0] = *(const f32x4*)(xr + k);  XB[j][1] = *(const f32x4*)(xr + k + 4);
    WB[j][0] = *(const f32x4*)(wr + k);  WB[j][1] = *(const f32x4*)(wr + k + 4);
  }
#pragma unroll 4
  for (int s = 0; s < 24; ++s) {
    f32x4 xa = XB[s & 3][0], xb = XB[s & 3][1];
    f32x4 wa = WB[s & 3][0], wb2 = WB[s & 3][1];
    if (s + 4 <= 24) {   // prefetch stage s+4 (stage 24 clamped)
      const int kn = (s + 4) * 32 + quad * 8;
      const int kc = (kn > 776) ? 776 : kn;
      XB[s & 3][0] = *(const f32x4*)(xr + kc);  XB[s & 3][1] = *(const f32x4*)(xr + kc + 4);
      WB[s & 3][0] = *(const f32x4*)(wr + kc);  WB[s & 3][1] = *(const f32x4*)(wr + kc + 4);
    }
    f16x8 ahi = cvt8(xa, xb);
    f16x8 alo = res8(xa, xb, ahi);
    f16x8 bh  = cvt8(wa, wb2);
    acc  = MFMA(ahi, bh, acc);
    acc2 = MFMA(alo, bh, acc2);   // two independent chains
  }
  {   // s = 24: k = 768 + quad*8; quads 2,3 out of range -> zero A
    f32x4 xa = XB[0][0], xb = XB[0][1];
    f32x4 wa = WB[0][0], wb2 = WB[0][1];
    f16x8 ahi = cvt8(xa, xb);
    f16x8 alo = res8(xa, xb, ahi);
    if (quad >= 2) { ahi = (f16x8){}; alo = (f16x8){}; }  // wave-uniform per quad
    f16x8 bh = cvt8(wa, wb2);
    acc  = MFMA(ahi, bh, acc);
    acc2 = MFMA(alo, bh, acc2);
  }
  f32x4 xf;   // fixed-point input, f32, D-layout
#pragma unroll
  for (int i = 0; i < 4; ++i) xf[i] = acc[i] + acc2[i] + bi;

  // unconditional A-frag read: rows 8..15 duplicate rows 0..7 (garbage-OK)
#define ZREAD(pbuf, off) (*(const f16x8*)&Zb[pbuf][lo16 & 7][(off) + quad * 8])

  // ---- z0 for wb=0 into buf 0 (s_0 = 0) ----
  if (quad < 2) {
#pragma unroll
    for (int i = 0; i < 4; ++i)
      Zb[0][quad * 4 + i][u0 + lo16] = (_Float16)tanh_fast(xf[i]);
  }
  __syncthreads();

  // ---- 4 implicit blocks: z = tanh(z @ W.T + xf), Picard ----
  // Parity: wb starts on buf s_wb = wb&1 (7 rounds flip parity per block).
#pragma unroll
  for (int wb = 0; wb < 4; ++wb) {
    const int sp = wb & 1;    // constant-folded (wb loop fully unrolled)
    f16x8 wf[4];
#pragma unroll
    for (int s = 0; s < 4; ++s)
      wf[s] = cvt8(raw[s * 2], raw[s * 2 + 1]);
    if (wb < 3) {   // prefetch next W during this block's Picard loop
      const float* a = Ws[wb + 1] + (size_t)(u0 + lo16) * UNITS;
#pragma unroll
      for (int s = 0; s < 4; ++s) {
        const int k = s * 32 + quad * 8;
        raw[s * 2]     = *(const f32x4*)(a + k);
        raw[s * 2 + 1] = *(const f32x4*)(a + k + 4);
      }
    }

#pragma unroll
    for (int it = 0; it < NIT - 1; ++it) {        // 6 in-loop rounds
      const int p = (sp + it) & 1;
      f16x8 a0 = ZREAD(p, 0);
      f16x8 a1 = ZREAD(p, 32);
      f16x8 a2 = ZREAD(p, 64);
      f16x8 a3 = ZREAD(p, 96);
      f32x4 chi = xf;                         // chain 1: xf + A0W0 + A1W1
      f32x4 clo = {0.f, 0.f, 0.f, 0.f};       // chain 2: A2W2 + A3W3
      chi = MFMA(a0, wf[0], chi);
      clo = MFMA(a2, wf[2], clo);
      chi = MFMA(a1, wf[1], chi);
      clo = MFMA(a3, wf[3], clo);
      const int q = p ^ 1;
      if (quad < 2) {
#pragma unroll
        for (int i = 0; i < 4; ++i)
          Zb[q][quad * 4 + i][u0 + lo16] = (_Float16)tanh_fast(chi[i] + clo[i]);
      }
      __syncthreads();
    }
    // final iteration: reads buf (sp+6)&1 = sp; output tanh stays f32 -> xf.
    // wb<3: write next z0 = tanh(xf') to buf sp^1 (its last readers were at
    // it=5 and passed that barrier -> race-free; next wb starts on sp^1 ✓).
    // wb==3 (sp=1): write z4 itself to buf 0 for the head.
    {
      f16x8 a0 = ZREAD(sp, 0);
      f16x8 a1 = ZREAD(sp, 32);
      f16x8 a2 = ZREAD(sp, 64);
      f16x8 a3 = ZREAD(sp, 96);
      f32x4 chi = xf;
      f32x4 clo = {0.f, 0.f, 0.f, 0.f};
      chi = MFMA(a0, wf[0], chi);
      clo = MFMA(a2, wf[2], clo);
      chi = MFMA(a1, wf[1], chi);
      clo = MFMA(a3, wf[3], clo);
#pragma unroll
      for (int i = 0; i < 4; ++i) xf[i] = tanh_fast(chi[i] + clo[i]);
      if (quad < 2) {
#pragma unroll
        for (int i = 0; i < 4; ++i)
          Zb[sp ^ 1][quad * 4 + i][u0 + lo16] =
              (_Float16)((wb < 3) ? tanh_fast(xf[i]) : xf[i]);
      }
      __syncthreads();
    }
  }

  // ---- head (wave 0 only): logits = z4 @ W_out.T + b_out via MFMA, softmax ----
  if (wave == 0) {
    const int cls = (lo16 < D_OUT) ? lo16 : 0;
    const float* wo = W_out + (size_t)cls * UNITS;
    f16x8 bf[4];
#pragma unroll
    for (int s = 0; s < 4; ++s) {
      const int k = s * 32 + quad * 8;
      bf[s] = cvt8(*(const f32x4*)(wo + k), *(const f32x4*)(wo + k + 4));
      if (lo16 >= D_OUT) bf[s] = (f16x8){};
    }
    const float bo = b_out[cls];
    f16x8 a0 = ZREAD(0, 0);
    f16x8 a1 = ZREAD(0, 32);
    f16x8 a2 = ZREAD(0, 64);
    f16x8 a3 = ZREAD(0, 96);
    f32x4 c = {0.f, 0.f, 0.f, 0.f};
    c = MFMA(a0, bf[0], c);
    c = MFMA(a1, bf[1], c);
    c = MFMA(a2, bf[2], c);
    c = MFMA(a3, bf[3], c);
    // D[m=quad*4+i][n=lo16]: rows 0..7 real (quads 0,1), classes lo16<10
    float pr[4];
#pragma unroll
    for (int i = 0; i < 4; ++i) {
      float v = (lo16 < D_OUT) ? (c[i] + bo) : -1e30f;
      float m = v;
#pragma unroll
      for (int d = 1; d < 16; d <<= 1) m = fmaxf(m, __shfl_xor(m, d, 16));
      float e = (lo16 < D_OUT) ? __expf(v - m) : 0.f;
      float sm = e;
#pragma unroll
      for (int d = 1; d < 16; d <<= 1) sm += __shfl_xor(sm, d, 16);
      pr[i] = e * rcp_fast(sm);
    }
    if (quad < 2 && lo16 < D_OUT) {
#pragma unroll
      for (int i = 0; i < 4; ++i)
        out[(size_t)(r0 + quad * 4 + i) * D_OUT + lo16] = pr[i];
    }
  }
}

extern "C" void kernel_launch(void* const* d_in, const int* in_sizes, int n_in,
                              void* d_out, int out_size, void* d_ws, size_t ws_size,
                              hipStream_t stream) {
  const float* x     = (const float*)d_in[0];
  const float* W_in  = (const float*)d_in[1];
  const float* b_in  = (const float*)d_in[2];
  const float* W1    = (const float*)d_in[3];
  const float* W2    = (const float*)d_in[4];
  const float* W3    = (const float*)d_in[5];
  const float* W4    = (const float*)d_in[6];
  const float* W_out = (const float*)d_in[7];
  const float* b_out = (const float*)d_in[8];
  float* outp = (float*)d_out;

  dim3 grid(B_ROWS / RPB);      // 256 blocks x 8 waves, full chip
  dim3 block(THREADS);
  hipLaunchKernelGGL(fused_net, grid, block, 0, stream,
                     x, W_in, b_in, W1, W2, W3, W4, W_out, b_out, outp);
}

// Round 14
// 97.617 us; speedup vs baseline: 1.2251x; 1.0157x over previous
//
#include <hip/hip_runtime.h>

// NewtonImplicitNet via Picard iteration, MFMA, 24-round edition.
// R13 post-mortem: absmax UNCHANGED at 1.95e-3 for NIT=7 -> that level is
// the 2-term input-GEMM W-rounding floor; Picard residual at 7 is below it.
// Per-round instruction count is at the layout floor (4 b128 read + 4 b16
// masked write + 4 MFMA + 4 tanh; exec-masked writes issue regardless).
// R14: NIT 7->6 (28->24 rounds). residual(6) ~ residual(7)/rho <~ 3e-3,
// total <~ 4e-3 vs 7.8e-3 threshold. Even NIT -> simple parity (z0 buf0,
// final reads buf1, next-z0 to buf0 behind the it=NIT-2 barrier).

#define B_ROWS  2048
#define D_IN    784
#define UNITS   128
#define D_OUT   10
#define RPB     8       // rows per block -> 256 blocks, rows 0..7 real in M=16
#define THREADS 512
#define NIT     6       // even (buffer parity: final read = buf 1, z0 -> buf 0)
#define ZSTR    138     // f16 Z row stride: 69 dwords = 5 mod 32 (2-way max)

typedef _Float16 f16x8 __attribute__((ext_vector_type(8)));
typedef float    f32x4 __attribute__((ext_vector_type(4)));

__device__ __forceinline__ float rcp_fast(float x) { return __builtin_amdgcn_rcpf(x); }

__device__ __forceinline__ float tanh_fast(float x) {
  float e = __expf(2.0f * x);
  return 1.0f - 2.0f * rcp_fast(e + 1.0f);
}

__device__ __forceinline__ f16x8 cvt8(f32x4 a, f32x4 b) {
  f16x8 r;
  r[0] = (_Float16)a[0]; r[1] = (_Float16)a[1]; r[2] = (_Float16)a[2]; r[3] = (_Float16)a[3];
  r[4] = (_Float16)b[0]; r[5] = (_Float16)b[1]; r[6] = (_Float16)b[2]; r[7] = (_Float16)b[3];
  return r;
}
__device__ __forceinline__ f16x8 res8(f32x4 a, f32x4 b, f16x8 hi) {
  f16x8 r;
  r[0] = (_Float16)(a[0] - (float)hi[0]); r[1] = (_Float16)(a[1] - (float)hi[1]);
  r[2] = (_Float16)(a[2] - (float)hi[2]); r[3] = (_Float16)(a[3] - (float)hi[3]);
  r[4] = (_Float16)(b[0] - (float)hi[4]); r[5] = (_Float16)(b[1] - (float)hi[5]);
  r[6] = (_Float16)(b[2] - (float)hi[6]); r[7] = (_Float16)(b[3] - (float)hi[7]);
  return r;
}

#define MFMA(a, b, c) __builtin_amdgcn_mfma_f32_16x16x32_f16((a), (b), (c), 0, 0, 0)

// Fragment conventions (validated R4-R13):
//   A: lane holds A[m=lo16][k = 32s + quad*8 + j], j=0..7
//   B: lane holds B[k = 32s + quad*8 + j][n=lo16]  (= Wrow[n][k..] row-major)
//   C/D: lane holds D[m = quad*4 + i][n=lo16], i=0..3
// D rows depend only on A rows -> A rows 8..15 may hold garbage (dup of 0..7).

__global__ __launch_bounds__(THREADS, 1) void fused_net(
    const float* __restrict__ x,
    const float* __restrict__ W_in,
    const float* __restrict__ b_in,
    const float* __restrict__ W1,
    const float* __restrict__ W2,
    const float* __restrict__ W3,
    const float* __restrict__ W4,
    const float* __restrict__ W_out,
    const float* __restrict__ b_out,
    float* __restrict__ out)
{
  __shared__ __align__(16) _Float16 Zb[2][RPB][ZSTR];  // the only LDS (~4.4 KB)

  const int t    = threadIdx.x;
  const int wave = t >> 6;        // 0..7, N-tile: units [16w, 16w+16)
  const int l    = t & 63;
  const int lo16 = l & 15;
  const int quad = l >> 4;
  const int u0   = wave * 16;
  const int r0   = blockIdx.x * RPB;

  const float bi = b_in[u0 + lo16];   // early scalar load

  const float* const Ws[4] = {W1, W2, W3, W4};

  // ---- prefetch W-frag raw data for wb=0 (consumed after input GEMM) ----
  f32x4 raw[8];
  {
    const float* a = Ws[0] + (size_t)(u0 + lo16) * UNITS;
#pragma unroll
    for (int s = 0; s < 4; ++s) {
      const int k = s * 32 + quad * 8;
      raw[s * 2]     = *(const f32x4*)(a + k);
      raw[s * 2 + 1] = *(const f32x4*)(a + k + 4);
    }
  }

  // ---- input GEMM: xf = x @ W_in.T + b_in (2-term: x hi/lo @ W f16) ----
  // Rows: lane lo16&7 -> rows 8..15 duplicate rows 0..7 (garbage D rows, OK).
  // s = 0..23 fully valid; s=24 masked epilogue (quads 2,3 out of range).
  f32x4 acc  = {0.f, 0.f, 0.f, 0.f};
  f32x4 acc2 = {0.f, 0.f, 0.f, 0.f};
  const float* xr = x    + (size_t)(r0 + (lo16 & 7)) * D_IN;
  const float* wr = W_in + (size_t)(u0 + lo16) * D_IN;
  f32x4 XB[4][2], WB[4][2];   // depth-4 prefetch ring
#pragma unroll
  for (int j = 0; j < 4; ++j) {
    const int k = j * 32 + quad * 8;
    XB[j][0] = *(const f32x4*)(xr + k);  XB[j][1] = *(const f32x4*)(xr + k + 4);
    WB[j][0] = *(const f32x4*)(wr + k);  WB[j][1] = *(const f32x4*)(wr + k + 4);
  }
#pragma unroll 4
  for (int s = 0; s < 24; ++s) {
    f32x4 xa = XB[s & 3][0], xb = XB[s & 3][1];
    f32x4 wa = WB[s & 3][0], wb2 = WB[s & 3][1];
    if (s + 4 <= 24) {   // prefetch stage s+4 (stage 24 clamped)
      const int kn = (s + 4) * 32 + quad * 8;
      const int kc = (kn > 776) ? 776 : kn;
      XB[s & 3][0] = *(const f32x4*)(xr + kc);  XB[s & 3][1] = *(const f32x4*)(xr + kc + 4);
      WB[s & 3][0] = *(const f32x4*)(wr + kc);  WB[s & 3][1] = *(const f32x4*)(wr + kc + 4);
    }
    f16x8 ahi = cvt8(xa, xb);
    f16x8 alo = res8(xa, xb, ahi);
    f16x8 bh  = cvt8(wa, wb2);
    acc  = MFMA(ahi, bh, acc);
    acc2 = MFMA(alo, bh, acc2);   // two independent chains
  }
  {   // s = 24: k = 768 + quad*8; quads 2,3 out of range -> zero A
    f32x4 xa = XB[0][0], xb = XB[0][1];
    f32x4 wa = WB[0][0], wb2 = WB[0][1];
    f16x8 ahi = cvt8(xa, xb);
    f16x8 alo = res8(xa, xb, ahi);
    if (quad >= 2) { ahi = (f16x8){}; alo = (f16x8){}; }  // wave-uniform per quad
    f16x8 bh = cvt8(wa, wb2);
    acc  = MFMA(ahi, bh, acc);
    acc2 = MFMA(alo, bh, acc2);
  }
  f32x4 xf;   // fixed-point input, f32, D-layout
#pragma unroll
  for (int i = 0; i < 4; ++i) xf[i] = acc[i] + acc2[i] + bi;

  // unconditional A-frag read: rows 8..15 duplicate rows 0..7 (garbage-OK)
#define ZREAD(pbuf, off) (*(const f16x8*)&Zb[pbuf][lo16 & 7][(off) + quad * 8])

  // ---- z0 for wb=0 into buf 0 ----
  if (quad < 2) {
#pragma unroll
    for (int i = 0; i < 4; ++i)
      Zb[0][quad * 4 + i][u0 + lo16] = (_Float16)tanh_fast(xf[i]);
  }
  __syncthreads();

  // ---- 4 implicit blocks: z = tanh(z @ W.T + xf), Picard ----
#pragma unroll
  for (int wb = 0; wb < 4; ++wb) {
    f16x8 wf[4];
#pragma unroll
    for (int s = 0; s < 4; ++s)
      wf[s] = cvt8(raw[s * 2], raw[s * 2 + 1]);
    if (wb < 3) {   // prefetch next W during this block's Picard loop
      const float* a = Ws[wb + 1] + (size_t)(u0 + lo16) * UNITS;
#pragma unroll
      for (int s = 0; s < 4; ++s) {
        const int k = s * 32 + quad * 8;
        raw[s * 2]     = *(const f32x4*)(a + k);
        raw[s * 2 + 1] = *(const f32x4*)(a + k + 4);
      }
    }

#pragma unroll
    for (int it = 0; it < NIT - 1; ++it) {        // 5 in-loop rounds
      const int p = it & 1;
      f16x8 a0 = ZREAD(p, 0);
      f16x8 a1 = ZREAD(p, 32);
      f16x8 a2 = ZREAD(p, 64);
      f16x8 a3 = ZREAD(p, 96);
      f32x4 chi = xf;                         // chain 1: xf + A0W0 + A1W1
      f32x4 clo = {0.f, 0.f, 0.f, 0.f};       // chain 2: A2W2 + A3W3
      chi = MFMA(a0, wf[0], chi);
      clo = MFMA(a2, wf[2], clo);
      chi = MFMA(a1, wf[1], chi);
      clo = MFMA(a3, wf[3], clo);
      const int q = p ^ 1;
      if (quad < 2) {
#pragma unroll
        for (int i = 0; i < 4; ++i)
          Zb[q][quad * 4 + i][u0 + lo16] = (_Float16)tanh_fast(chi[i] + clo[i]);
      }
      __syncthreads();
    }
    // final iteration (reads buf (NIT-1)&1 = 1): output tanh stays f32 -> xf.
    // wb<3: write next z0 = tanh(xf') to buf 0 (last readers passed the
    // it=NIT-2 barrier -> race-free); wb==3: write z4 itself (head reads buf 0).
    {
      f16x8 a0 = ZREAD(1, 0);
      f16x8 a1 = ZREAD(1, 32);
      f16x8 a2 = ZREAD(1, 64);
      f16x8 a3 = ZREAD(1, 96);
      f32x4 chi = xf;
      f32x4 clo = {0.f, 0.f, 0.f, 0.f};
      chi = MFMA(a0, wf[0], chi);
      clo = MFMA(a2, wf[2], clo);
      chi = MFMA(a1, wf[1], chi);
      clo = MFMA(a3, wf[3], clo);
#pragma unroll
      for (int i = 0; i < 4; ++i) xf[i] = tanh_fast(chi[i] + clo[i]);
      if (quad < 2) {
#pragma unroll
        for (int i = 0; i < 4; ++i)
          Zb[0][quad * 4 + i][u0 + lo16] =
              (_Float16)((wb < 3) ? tanh_fast(xf[i]) : xf[i]);
      }
      __syncthreads();
    }
  }

  // ---- head (wave 0 only): logits = z4 @ W_out.T + b_out via MFMA, softmax ----
  if (wave == 0) {
    const int cls = (lo16 < D_OUT) ? lo16 : 0;
    const float* wo = W_out + (size_t)cls * UNITS;
    f16x8 bf[4];
#pragma unroll
    for (int s = 0; s < 4; ++s) {
      const int k = s * 32 + quad * 8;
      bf[s] = cvt8(*(const f32x4*)(wo + k), *(const f32x4*)(wo + k + 4));
      if (lo16 >= D_OUT) bf[s] = (f16x8){};
    }
    const float bo = b_out[cls];
    f16x8 a0 = ZREAD(0, 0);
    f16x8 a1 = ZREAD(0, 32);
    f16x8 a2 = ZREAD(0, 64);
    f16x8 a3 = ZREAD(0, 96);
    f32x4 c = {0.f, 0.f, 0.f, 0.f};
    c = MFMA(a0, bf[0], c);
    c = MFMA(a1, bf[1], c);
    c = MFMA(a2, bf[2], c);
    c = MFMA(a3, bf[3], c);
    // D[m=quad*4+i][n=lo16]: rows 0..7 real (quads 0,1), classes lo16<10
    float pr[4];
#pragma unroll
    for (int i = 0; i < 4; ++i) {
      float v = (lo16 < D_OUT) ? (c[i] + bo) : -1e30f;
      float m = v;
#pragma unroll
      for (int d = 1; d < 16; d <<= 1) m = fmaxf(m, __shfl_xor(m, d, 16));
      float e = (lo16 < D_OUT) ? __expf(v - m) : 0.f;
      float sm = e;
#pragma unroll
      for (int d = 1; d < 16; d <<= 1) sm += __shfl_xor(sm, d, 16);
      pr[i] = e * rcp_fast(sm);
    }
    if (quad < 2 && lo16 < D_OUT) {
#pragma unroll
      for (int i = 0; i < 4; ++i)
        out[(size_t)(r0 + quad * 4 + i) * D_OUT + lo16] = pr[i];
    }
  }
}

extern "C" void kernel_launch(void* const* d_in, const int* in_sizes, int n_in,
                              void* d_out, int out_size, void* d_ws, size_t ws_size,
                              hipStream_t stream) {
  const float* x     = (const float*)d_in[0];
  const float* W_in  = (const float*)d_in[1];
  const float* b_in  = (const float*)d_in[2];
  const float* W1    = (const float*)d_in[3];
  const float* W2    = (const float*)d_in[4];
  const float* W3    = (const float*)d_in[5];
  const float* W4    = (const float*)d_in[6];
  const float* W_out = (const float*)d_in[7];
  const float* b_out = (const float*)d_in[8];
  float* outp = (float*)d_out;

  dim3 grid(B_ROWS / RPB);      // 256 blocks x 8 waves, full chip
  dim3 block(THREADS);
  hipLaunchKernelGGL(fused_net, grid, block, 0, stream,
                     x, W_in, b_in, W1, W2, W3, W4, W_out, b_out, outp);
}

// Round 15
// 96.586 us; speedup vs baseline: 1.2382x; 1.0107x over previous
//
#include <hip/hip_runtime.h>

// NewtonImplicitNet via Picard iteration, MFMA, 20-round edition.
// R14 post-mortem: absmax STILL 1.95e-3 at NIT=6 -> residual(6) below the
// input-GEMM f16-W floor; effective contraction rho <~ 0.3. Bank conflicts
// now 0; VALUBusy 16% / MfmaUtil 3.8% / HBM 1.7% -> pure latency-bound
// structure (barrier rounds + prologue), no HW pipe near saturation.
// R15: NIT 6->5 (24->20 rounds). residual(5) <= residual(6)/rho ~ 3.3e-3,
// total <= ~6e-3 < 7.8e-3 (fallback NIT=6 if bust). Odd NIT via the
// R13-validated alternating parity sp = wb&1, constant-folded.

#define B_ROWS  2048
#define D_IN    784
#define UNITS   128
#define D_OUT   10
#define RPB     8       // rows per block -> 256 blocks, rows 0..7 real in M=16
#define THREADS 512
#define NIT     5       // odd: per-wb parity alternates (sp = wb&1)
#define ZSTR    138     // f16 Z row stride: 69 dwords = 5 mod 32 (2-way max)

typedef _Float16 f16x8 __attribute__((ext_vector_type(8)));
typedef float    f32x4 __attribute__((ext_vector_type(4)));

__device__ __forceinline__ float rcp_fast(float x) { return __builtin_amdgcn_rcpf(x); }

__device__ __forceinline__ float tanh_fast(float x) {
  float e = __expf(2.0f * x);
  return 1.0f - 2.0f * rcp_fast(e + 1.0f);
}

__device__ __forceinline__ f16x8 cvt8(f32x4 a, f32x4 b) {
  f16x8 r;
  r[0] = (_Float16)a[0]; r[1] = (_Float16)a[1]; r[2] = (_Float16)a[2]; r[3] = (_Float16)a[3];
  r[4] = (_Float16)b[0]; r[5] = (_Float16)b[1]; r[6] = (_Float16)b[2]; r[7] = (_Float16)b[3];
  return r;
}
__device__ __forceinline__ f16x8 res8(f32x4 a, f32x4 b, f16x8 hi) {
  f16x8 r;
  r[0] = (_Float16)(a[0] - (float)hi[0]); r[1] = (_Float16)(a[1] - (float)hi[1]);
  r[2] = (_Float16)(a[2] - (float)hi[2]); r[3] = (_Float16)(a[3] - (float)hi[3]);
  r[4] = (_Float16)(b[0] - (float)hi[4]); r[5] = (_Float16)(b[1] - (float)hi[5]);
  r[6] = (_Float16)(b[2] - (float)hi[6]); r[7] = (_Float16)(b[3] - (float)hi[7]);
  return r;
}

#define MFMA(a, b, c) __builtin_amdgcn_mfma_f32_16x16x32_f16((a), (b), (c), 0, 0, 0)

// Fragment conventions (validated R4-R14):
//   A: lane holds A[m=lo16][k = 32s + quad*8 + j], j=0..7
//   B: lane holds B[k = 32s + quad*8 + j][n=lo16]  (= Wrow[n][k..] row-major)
//   C/D: lane holds D[m = quad*4 + i][n=lo16], i=0..3
// D rows depend only on A rows -> A rows 8..15 may hold garbage (dup of 0..7).

__global__ __launch_bounds__(THREADS, 1) void fused_net(
    const float* __restrict__ x,
    const float* __restrict__ W_in,
    const float* __restrict__ b_in,
    const float* __restrict__ W1,
    const float* __restrict__ W2,
    const float* __restrict__ W3,
    const float* __restrict__ W4,
    const float* __restrict__ W_out,
    const float* __restrict__ b_out,
    float* __restrict__ out)
{
  __shared__ __align__(16) _Float16 Zb[2][RPB][ZSTR];  // the only LDS (~4.4 KB)

  const int t    = threadIdx.x;
  const int wave = t >> 6;        // 0..7, N-tile: units [16w, 16w+16)
  const int l    = t & 63;
  const int lo16 = l & 15;
  const int quad = l >> 4;
  const int u0   = wave * 16;
  const int r0   = blockIdx.x * RPB;

  const float bi = b_in[u0 + lo16];   // early scalar load

  const float* const Ws[4] = {W1, W2, W3, W4};

  // ---- prefetch W-frag raw data for wb=0 (consumed after input GEMM) ----
  f32x4 raw[8];
  {
    const float* a = Ws[0] + (size_t)(u0 + lo16) * UNITS;
#pragma unroll
    for (int s = 0; s < 4; ++s) {
      const int k = s * 32 + quad * 8;
      raw[s * 2]     = *(const f32x4*)(a + k);
      raw[s * 2 + 1] = *(const f32x4*)(a + k + 4);
    }
  }

  // ---- input GEMM: xf = x @ W_in.T + b_in (2-term: x hi/lo @ W f16) ----
  // Rows: lane lo16&7 -> rows 8..15 duplicate rows 0..7 (garbage D rows, OK).
  // s = 0..23 fully valid; s=24 masked epilogue (quads 2,3 out of range).
  f32x4 acc  = {0.f, 0.f, 0.f, 0.f};
  f32x4 acc2 = {0.f, 0.f, 0.f, 0.f};
  const float* xr = x    + (size_t)(r0 + (lo16 & 7)) * D_IN;
  const float* wr = W_in + (size_t)(u0 + lo16) * D_IN;
  f32x4 XB[4][2], WB[4][2];   // depth-4 prefetch ring
#pragma unroll
  for (int j = 0; j < 4; ++j) {
    const int k = j * 32 + quad * 8;
    XB[j][0] = *(const f32x4*)(xr + k);  XB[j][1] = *(const f32x4*)(xr + k + 4);
    WB[j][0] = *(const f32x4*)(wr + k);  WB[j][1] = *(const f32x4*)(wr + k + 4);
  }
#pragma unroll 4
  for (int s = 0; s < 24; ++s) {
    f32x4 xa = XB[s & 3][0], xb = XB[s & 3][1];
    f32x4 wa = WB[s & 3][0], wb2 = WB[s & 3][1];
    if (s + 4 <= 24) {   // prefetch stage s+4 (stage 24 clamped)
      const int kn = (s + 4) * 32 + quad * 8;
      const int kc = (kn > 776) ? 776 : kn;
      XB[s & 3][0] = *(const f32x4*)(xr + kc);  XB[s & 3][1] = *(const f32x4*)(xr + kc + 4);
      WB[s & 3][0] = *(const f32x4*)(wr + kc);  WB[s & 3][1] = *(const f32x4*)(wr + kc + 4);
    }
    f16x8 ahi = cvt8(xa, xb);
    f16x8 alo = res8(xa, xb, ahi);
    f16x8 bh  = cvt8(wa, wb2);
    acc  = MFMA(ahi, bh, acc);
    acc2 = MFMA(alo, bh, acc2);   // two independent chains
  }
  {   // s = 24: k = 768 + quad*8; quads 2,3 out of range -> zero A
    f32x4 xa = XB[0][0], xb = XB[0][1];
    f32x4 wa = WB[0][0], wb2 = WB[0][1];
    f16x8 ahi = cvt8(xa, xb);
    f16x8 alo = res8(xa, xb, ahi);
    if (quad >= 2) { ahi = (f16x8){}; alo = (f16x8){}; }  // wave-uniform per quad
    f16x8 bh = cvt8(wa, wb2);
    acc  = MFMA(ahi, bh, acc);
    acc2 = MFMA(alo, bh, acc2);
  }
  f32x4 xf;   // fixed-point input, f32, D-layout
#pragma unroll
  for (int i = 0; i < 4; ++i) xf[i] = acc[i] + acc2[i] + bi;

  // unconditional A-frag read: rows 8..15 duplicate rows 0..7 (garbage-OK)
#define ZREAD(pbuf, off) (*(const f16x8*)&Zb[pbuf][lo16 & 7][(off) + quad * 8])

  // ---- z0 for wb=0 into buf 0 ----
  if (quad < 2) {
#pragma unroll
    for (int i = 0; i < 4; ++i)
      Zb[0][quad * 4 + i][u0 + lo16] = (_Float16)tanh_fast(xf[i]);
  }
  __syncthreads();

  // ---- 4 implicit blocks: z = tanh(z @ W.T + xf), Picard ----
  // Parity: wb starts on buf sp = wb&1 (odd NIT flips parity per block).
#pragma unroll
  for (int wb = 0; wb < 4; ++wb) {
    const int sp = wb & 1;    // constant-folded (wb loop fully unrolled)
    f16x8 wf[4];
#pragma unroll
    for (int s = 0; s < 4; ++s)
      wf[s] = cvt8(raw[s * 2], raw[s * 2 + 1]);
    if (wb < 3) {   // prefetch next W during this block's Picard loop
      const float* a = Ws[wb + 1] + (size_t)(u0 + lo16) * UNITS;
#pragma unroll
      for (int s = 0; s < 4; ++s) {
        const int k = s * 32 + quad * 8;
        raw[s * 2]     = *(const f32x4*)(a + k);
        raw[s * 2 + 1] = *(const f32x4*)(a + k + 4);
      }
    }

#pragma unroll
    for (int it = 0; it < NIT - 1; ++it) {        // 4 in-loop rounds
      const int p = (sp + it) & 1;
      f16x8 a0 = ZREAD(p, 0);
      f16x8 a1 = ZREAD(p, 32);
      f16x8 a2 = ZREAD(p, 64);
      f16x8 a3 = ZREAD(p, 96);
      f32x4 chi = xf;                         // chain 1: xf + A0W0 + A1W1
      f32x4 clo = {0.f, 0.f, 0.f, 0.f};       // chain 2: A2W2 + A3W3
      chi = MFMA(a0, wf[0], chi);
      clo = MFMA(a2, wf[2], clo);
      chi = MFMA(a1, wf[1], chi);
      clo = MFMA(a3, wf[3], clo);
      const int q = p ^ 1;
      if (quad < 2) {
#pragma unroll
        for (int i = 0; i < 4; ++i)
          Zb[q][quad * 4 + i][u0 + lo16] = (_Float16)tanh_fast(chi[i] + clo[i]);
      }
      __syncthreads();
    }
    // final iteration: reads buf (sp + NIT-1)&1 = sp; output tanh stays f32.
    // wb<3: write next z0 = tanh(xf') to buf sp^1 (its last readers were at
    // it=NIT-2 and passed that barrier -> race-free; next wb starts on sp^1).
    // wb==3 (sp=1): write z4 itself to buf 0 for the head.
    {
      f16x8 a0 = ZREAD(sp, 0);
      f16x8 a1 = ZREAD(sp, 32);
      f16x8 a2 = ZREAD(sp, 64);
      f16x8 a3 = ZREAD(sp, 96);
      f32x4 chi = xf;
      f32x4 clo = {0.f, 0.f, 0.f, 0.f};
      chi = MFMA(a0, wf[0], chi);
      clo = MFMA(a2, wf[2], clo);
      chi = MFMA(a1, wf[1], chi);
      clo = MFMA(a3, wf[3], clo);
#pragma unroll
      for (int i = 0; i < 4; ++i) xf[i] = tanh_fast(chi[i] + clo[i]);
      if (quad < 2) {
#pragma unroll
        for (int i = 0; i < 4; ++i)
          Zb[sp ^ 1][quad * 4 + i][u0 + lo16] =
              (_Float16)((wb < 3) ? tanh_fast(xf[i]) : xf[i]);
      }
      __syncthreads();
    }
  }

  // ---- head (wave 0 only): logits = z4 @ W_out.T + b_out via MFMA, softmax ----
  if (wave == 0) {
    const int cls = (lo16 < D_OUT) ? lo16 : 0;
    const float* wo = W_out + (size_t)cls * UNITS;
    f16x8 bf[4];
#pragma unroll
    for (int s = 0; s < 4; ++s) {
      const int k = s * 32 + quad * 8;
      bf[s] = cvt8(*(const f32x4*)(wo + k), *(const f32x4*)(wo + k + 4));
      if (lo16 >= D_OUT) bf[s] = (f16x8){};
    }
    const float bo = b_out[cls];
    f16x8 a0 = ZREAD(0, 0);
    f16x8 a1 = ZREAD(0, 32);
    f16x8 a2 = ZREAD(0, 64);
    f16x8 a3 = ZREAD(0, 96);
    f32x4 c = {0.f, 0.f, 0.f, 0.f};
    c = MFMA(a0, bf[0], c);
    c = MFMA(a1, bf[1], c);
    c = MFMA(a2, bf[2], c);
    c = MFMA(a3, bf[3], c);
    // D[m=quad*4+i][n=lo16]: rows 0..7 real (quads 0,1), classes lo16<10
    float pr[4];
#pragma unroll
    for (int i = 0; i < 4; ++i) {
      float v = (lo16 < D_OUT) ? (c[i] + bo) : -1e30f;
      float m = v;
#pragma unroll
      for (int d = 1; d < 16; d <<= 1) m = fmaxf(m, __shfl_xor(m, d, 16));
      float e = (lo16 < D_OUT) ? __expf(v - m) : 0.f;
      float sm = e;
#pragma unroll
      for (int d = 1; d < 16; d <<= 1) sm += __shfl_xor(sm, d, 16);
      pr[i] = e * rcp_fast(sm);
    }
    if (quad < 2 && lo16 < D_OUT) {
#pragma unroll
      for (int i = 0; i < 4; ++i)
        out[(size_t)(r0 + quad * 4 + i) * D_OUT + lo16] = pr[i];
    }
  }
}

extern "C" void kernel_launch(void* const* d_in, const int* in_sizes, int n_in,
                              void* d_out, int out_size, void* d_ws, size_t ws_size,
                              hipStream_t stream) {
  const float* x     = (const float*)d_in[0];
  const float* W_in  = (const float*)d_in[1];
  const float* b_in  = (const float*)d_in[2];
  const float* W1    = (const float*)d_in[3];
  const float* W2    = (const float*)d_in[4];
  const float* W3    = (const float*)d_in[5];
  const float* W4    = (const float*)d_in[6];
  const float* W_out = (const float*)d_in[7];
  const float* b_out = (const float*)d_in[8];
  float* outp = (float*)d_out;

  dim3 grid(B_ROWS / RPB);      // 256 blocks x 8 waves, full chip
  dim3 block(THREADS);
  hipLaunchKernelGGL(fused_net, grid, block, 0, stream,
                     x, W_in, b_in, W1, W2, W3, W4, W_out, b_out, outp);
}

// Round 16
// 94.903 us; speedup vs baseline: 1.2601x; 1.0177x over previous
//
#include <hip/hip_runtime.h>

// NewtonImplicitNet via Picard iteration, MFMA, 16-round edition.
// R15 post-mortem: absmax still 1.95e-3 at NIT=5 -> rho < 0.32 (calibrated:
// rho^5 * 0.3 < 1e-3). Per-round cost ~0.4us; main loop ~8us of ~33us
// dispatch; rest is prologue/epilogue latency + launch + DVFS.
// R16: (1) NIT 5->4 (20->16 rounds); residual(4) < 1e-3/0.32 ~ 3.1e-3,
// total ~5e-3 < 7.8e-3 (fallback NIT=5). Even parity (z0 buf0, final reads
// buf1, next-z0 buf0). (2) W_out/b_out head fragments hoisted to prologue
// registers on wave 0 (kills the ~900-cyc serialized epilogue load).

#define B_ROWS  2048
#define D_IN    784
#define UNITS   128
#define D_OUT   10
#define RPB     8       // rows per block -> 256 blocks, rows 0..7 real in M=16
#define THREADS 512
#define NIT     4       // even (buffer parity: final read = buf 1, z0 -> buf 0)
#define ZSTR    138     // f16 Z row stride: 69 dwords = 5 mod 32 (2-way max)

typedef _Float16 f16x8 __attribute__((ext_vector_type(8)));
typedef float    f32x4 __attribute__((ext_vector_type(4)));

__device__ __forceinline__ float rcp_fast(float x) { return __builtin_amdgcn_rcpf(x); }

__device__ __forceinline__ float tanh_fast(float x) {
  float e = __expf(2.0f * x);
  return 1.0f - 2.0f * rcp_fast(e + 1.0f);
}

__device__ __forceinline__ f16x8 cvt8(f32x4 a, f32x4 b) {
  f16x8 r;
  r[0] = (_Float16)a[0]; r[1] = (_Float16)a[1]; r[2] = (_Float16)a[2]; r[3] = (_Float16)a[3];
  r[4] = (_Float16)b[0]; r[5] = (_Float16)b[1]; r[6] = (_Float16)b[2]; r[7] = (_Float16)b[3];
  return r;
}
__device__ __forceinline__ f16x8 res8(f32x4 a, f32x4 b, f16x8 hi) {
  f16x8 r;
  r[0] = (_Float16)(a[0] - (float)hi[0]); r[1] = (_Float16)(a[1] - (float)hi[1]);
  r[2] = (_Float16)(a[2] - (float)hi[2]); r[3] = (_Float16)(a[3] - (float)hi[3]);
  r[4] = (_Float16)(b[0] - (float)hi[4]); r[5] = (_Float16)(b[1] - (float)hi[5]);
  r[6] = (_Float16)(b[2] - (float)hi[6]); r[7] = (_Float16)(b[3] - (float)hi[7]);
  return r;
}

#define MFMA(a, b, c) __builtin_amdgcn_mfma_f32_16x16x32_f16((a), (b), (c), 0, 0, 0)

// Fragment conventions (validated R4-R15):
//   A: lane holds A[m=lo16][k = 32s + quad*8 + j], j=0..7
//   B: lane holds B[k = 32s + quad*8 + j][n=lo16]  (= Wrow[n][k..] row-major)
//   C/D: lane holds D[m = quad*4 + i][n=lo16], i=0..3
// D rows depend only on A rows -> A rows 8..15 may hold garbage (dup of 0..7).

__global__ __launch_bounds__(THREADS, 1) void fused_net(
    const float* __restrict__ x,
    const float* __restrict__ W_in,
    const float* __restrict__ b_in,
    const float* __restrict__ W1,
    const float* __restrict__ W2,
    const float* __restrict__ W3,
    const float* __restrict__ W4,
    const float* __restrict__ W_out,
    const float* __restrict__ b_out,
    float* __restrict__ out)
{
  __shared__ __align__(16) _Float16 Zb[2][RPB][ZSTR];  // the only LDS (~4.4 KB)

  const int t    = threadIdx.x;
  const int wave = t >> 6;        // 0..7, N-tile: units [16w, 16w+16)
  const int l    = t & 63;
  const int lo16 = l & 15;
  const int quad = l >> 4;
  const int u0   = wave * 16;
  const int r0   = blockIdx.x * RPB;

  const float bi = b_in[u0 + lo16];   // early scalar load

  const float* const Ws[4] = {W1, W2, W3, W4};

  // ---- prefetch W-frag raw data for wb=0 (consumed after input GEMM) ----
  f32x4 raw[8];
  {
    const float* a = Ws[0] + (size_t)(u0 + lo16) * UNITS;
#pragma unroll
    for (int s = 0; s < 4; ++s) {
      const int k = s * 32 + quad * 8;
      raw[s * 2]     = *(const f32x4*)(a + k);
      raw[s * 2 + 1] = *(const f32x4*)(a + k + 4);
    }
  }

  // ---- head fragments hoisted: wave 0 loads W_out/b_out NOW (regs) ----
  f16x8 bf0 = {}, bf1 = {}, bf2 = {}, bf3 = {};
  float bo = 0.f;
  if (wave == 0) {
    const int cls = (lo16 < D_OUT) ? lo16 : 0;
    const float* wo = W_out + (size_t)cls * UNITS;
    if (lo16 < D_OUT) {
      bf0 = cvt8(*(const f32x4*)(wo + 0 * 32 + quad * 8),
                 *(const f32x4*)(wo + 0 * 32 + quad * 8 + 4));
      bf1 = cvt8(*(const f32x4*)(wo + 1 * 32 + quad * 8),
                 *(const f32x4*)(wo + 1 * 32 + quad * 8 + 4));
      bf2 = cvt8(*(const f32x4*)(wo + 2 * 32 + quad * 8),
                 *(const f32x4*)(wo + 2 * 32 + quad * 8 + 4));
      bf3 = cvt8(*(const f32x4*)(wo + 3 * 32 + quad * 8),
                 *(const f32x4*)(wo + 3 * 32 + quad * 8 + 4));
      bo  = b_out[cls];
    }
  }

  // ---- input GEMM: xf = x @ W_in.T + b_in (2-term: x hi/lo @ W f16) ----
  // Rows: lane lo16&7 -> rows 8..15 duplicate rows 0..7 (garbage D rows, OK).
  // s = 0..23 fully valid; s=24 masked epilogue (quads 2,3 out of range).
  f32x4 acc  = {0.f, 0.f, 0.f, 0.f};
  f32x4 acc2 = {0.f, 0.f, 0.f, 0.f};
  const float* xr = x    + (size_t)(r0 + (lo16 & 7)) * D_IN;
  const float* wr = W_in + (size_t)(u0 + lo16) * D_IN;
  f32x4 XB[4][2], WB[4][2];   // depth-4 prefetch ring
#pragma unroll
  for (int j = 0; j < 4; ++j) {
    const int k = j * 32 + quad * 8;
    XB[j][0] = *(const f32x4*)(xr + k);  XB[j][1] = *(const f32x4*)(xr + k + 4);
    WB[j][0] = *(const f32x4*)(wr + k);  WB[j][1] = *(const f32x4*)(wr + k + 4);
  }
#pragma unroll 4
  for (int s = 0; s < 24; ++s) {
    f32x4 xa = XB[s & 3][0], xb = XB[s & 3][1];
    f32x4 wa = WB[s & 3][0], wb2 = WB[s & 3][1];
    if (s + 4 <= 24) {   // prefetch stage s+4 (stage 24 clamped)
      const int kn = (s + 4) * 32 + quad * 8;
      const int kc = (kn > 776) ? 776 : kn;
      XB[s & 3][0] = *(const f32x4*)(xr + kc);  XB[s & 3][1] = *(const f32x4*)(xr + kc + 4);
      WB[s & 3][0] = *(const f32x4*)(wr + kc);  WB[s & 3][1] = *(const f32x4*)(wr + kc + 4);
    }
    f16x8 ahi = cvt8(xa, xb);
    f16x8 alo = res8(xa, xb, ahi);
    f16x8 bh  = cvt8(wa, wb2);
    acc  = MFMA(ahi, bh, acc);
    acc2 = MFMA(alo, bh, acc2);   // two independent chains
  }
  {   // s = 24: k = 768 + quad*8; quads 2,3 out of range -> zero A
    f32x4 xa = XB[0][0], xb = XB[0][1];
    f32x4 wa = WB[0][0], wb2 = WB[0][1];
    f16x8 ahi = cvt8(xa, xb);
    f16x8 alo = res8(xa, xb, ahi);
    if (quad >= 2) { ahi = (f16x8){}; alo = (f16x8){}; }  // wave-uniform per quad
    f16x8 bh = cvt8(wa, wb2);
    acc  = MFMA(ahi, bh, acc);
    acc2 = MFMA(alo, bh, acc2);
  }
  f32x4 xf;   // fixed-point input, f32, D-layout
#pragma unroll
  for (int i = 0; i < 4; ++i) xf[i] = acc[i] + acc2[i] + bi;

  // unconditional A-frag read: rows 8..15 duplicate rows 0..7 (garbage-OK)
#define ZREAD(pbuf, off) (*(const f16x8*)&Zb[pbuf][lo16 & 7][(off) + quad * 8])

  // ---- z0 for wb=0 into buf 0 ----
  if (quad < 2) {
#pragma unroll
    for (int i = 0; i < 4; ++i)
      Zb[0][quad * 4 + i][u0 + lo16] = (_Float16)tanh_fast(xf[i]);
  }
  __syncthreads();

  // ---- 4 implicit blocks: z = tanh(z @ W.T + xf), Picard ----
#pragma unroll
  for (int wb = 0; wb < 4; ++wb) {
    f16x8 wf[4];
#pragma unroll
    for (int s = 0; s < 4; ++s)
      wf[s] = cvt8(raw[s * 2], raw[s * 2 + 1]);
    if (wb < 3) {   // prefetch next W during this block's Picard loop
      const float* a = Ws[wb + 1] + (size_t)(u0 + lo16) * UNITS;
#pragma unroll
      for (int s = 0; s < 4; ++s) {
        const int k = s * 32 + quad * 8;
        raw[s * 2]     = *(const f32x4*)(a + k);
        raw[s * 2 + 1] = *(const f32x4*)(a + k + 4);
      }
    }

#pragma unroll
    for (int it = 0; it < NIT - 1; ++it) {        // 3 in-loop rounds
      const int p = it & 1;
      f16x8 a0 = ZREAD(p, 0);
      f16x8 a1 = ZREAD(p, 32);
      f16x8 a2 = ZREAD(p, 64);
      f16x8 a3 = ZREAD(p, 96);
      f32x4 chi = xf;                         // chain 1: xf + A0W0 + A1W1
      f32x4 clo = {0.f, 0.f, 0.f, 0.f};       // chain 2: A2W2 + A3W3
      chi = MFMA(a0, wf[0], chi);
      clo = MFMA(a2, wf[2], clo);
      chi = MFMA(a1, wf[1], chi);
      clo = MFMA(a3, wf[3], clo);
      const int q = p ^ 1;
      if (quad < 2) {
#pragma unroll
        for (int i = 0; i < 4; ++i)
          Zb[q][quad * 4 + i][u0 + lo16] = (_Float16)tanh_fast(chi[i] + clo[i]);
      }
      __syncthreads();
    }
    // final iteration (reads buf (NIT-1)&1 = 1): output tanh stays f32 -> xf.
    // wb<3: write next z0 = tanh(xf') to buf 0 (last readers passed the
    // it=NIT-2 barrier -> race-free); wb==3: write z4 itself (head reads buf 0).
    {
      f16x8 a0 = ZREAD(1, 0);
      f16x8 a1 = ZREAD(1, 32);
      f16x8 a2 = ZREAD(1, 64);
      f16x8 a3 = ZREAD(1, 96);
      f32x4 chi = xf;
      f32x4 clo = {0.f, 0.f, 0.f, 0.f};
      chi = MFMA(a0, wf[0], chi);
      clo = MFMA(a2, wf[2], clo);
      chi = MFMA(a1, wf[1], chi);
      clo = MFMA(a3, wf[3], clo);
#pragma unroll
      for (int i = 0; i < 4; ++i) xf[i] = tanh_fast(chi[i] + clo[i]);
      if (quad < 2) {
#pragma unroll
        for (int i = 0; i < 4; ++i)
          Zb[0][quad * 4 + i][u0 + lo16] =
              (_Float16)((wb < 3) ? tanh_fast(xf[i]) : xf[i]);
      }
      __syncthreads();
    }
  }

  // ---- head (wave 0 only): logits via MFMA with prefetched frags, softmax ----
  if (wave == 0) {
    f16x8 a0 = ZREAD(0, 0);
    f16x8 a1 = ZREAD(0, 32);
    f16x8 a2 = ZREAD(0, 64);
    f16x8 a3 = ZREAD(0, 96);
    f32x4 c = {0.f, 0.f, 0.f, 0.f};
    c = MFMA(a0, bf0, c);
    c = MFMA(a1, bf1, c);
    c = MFMA(a2, bf2, c);
    c = MFMA(a3, bf3, c);
    // D[m=quad*4+i][n=lo16]: rows 0..7 real (quads 0,1), classes lo16<10
    float pr[4];
#pragma unroll
    for (int i = 0; i < 4; ++i) {
      float v = (lo16 < D_OUT) ? (c[i] + bo) : -1e30f;
      float m = v;
#pragma unroll
      for (int d = 1; d < 16; d <<= 1) m = fmaxf(m, __shfl_xor(m, d, 16));
      float e = (lo16 < D_OUT) ? __expf(v - m) : 0.f;
      float sm = e;
#pragma unroll
      for (int d = 1; d < 16; d <<= 1) sm += __shfl_xor(sm, d, 16);
      pr[i] = e * rcp_fast(sm);
    }
    if (quad < 2 && lo16 < D_OUT) {
#pragma unroll
      for (int i = 0; i < 4; ++i)
        out[(size_t)(r0 + quad * 4 + i) * D_OUT + lo16] = pr[i];
    }
  }
}

extern "C" void kernel_launch(void* const* d_in, const int* in_sizes, int n_in,
                              void* d_out, int out_size, void* d_ws, size_t ws_size,
                              hipStream_t stream) {
  const float* x     = (const float*)d_in[0];
  const float* W_in  = (const float*)d_in[1];
  const float* b_in  = (const float*)d_in[2];
  const float* W1    = (const float*)d_in[3];
  const float* W2    = (const float*)d_in[4];
  const float* W3    = (const float*)d_in[5];
  const float* W4    = (const float*)d_in[6];
  const float* W_out = (const float*)d_in[7];
  const float* b_out = (const float*)d_in[8];
  float* outp = (float*)d_out;

  dim3 grid(B_ROWS / RPB);      // 256 blocks x 8 waves, full chip
  dim3 block(THREADS);
  hipLaunchKernelGGL(fused_net, grid, block, 0, stream,
                     x, W_in, b_in, W1, W2, W3, W4, W_out, b_out, outp);
}